// Round 11
// baseline (333.615 us; speedup 1.0000x reference)
//
#include <hip/hip_runtime.h>

using bf16x8 = __attribute__((ext_vector_type(8))) short;
using bf16x4 = __attribute__((ext_vector_type(4))) short;
using f32x4  = __attribute__((ext_vector_type(4))) float;

#define NH    16
#define DKH   64
#define TTOT  2048
#define QL    1024

__device__ __forceinline__ float bf2f(unsigned short u) {
  union { unsigned int i; float f; } c; c.i = ((unsigned int)u) << 16; return c.f;
}
__device__ __forceinline__ unsigned short f2bf(float f) {
  union { float f; unsigned int i; } c; c.f = f;
  unsigned int x = c.i;
  x += 0x7fffu + ((x >> 16) & 1u);
  return (unsigned short)(x >> 16);
}
// HW packed f32->bf16. ORDER-INSENSITIVE uses only (R9 post-mortem):
// applied identically to both GEMM operands, a pairwise K-permutation cancels.
__device__ __forceinline__ unsigned int cvtpk(float lo, float hi) {
  unsigned int r;
  asm("v_cvt_pk_bf16_f32 %0, %1, %2" : "=v"(r) : "v"(lo), "v"(hi));
  return r;
}
// XOR swizzle inside each row (byte bits 4..6 ^= row&7) for 16x2048 bf16 LDS rows
__device__ __forceinline__ int swz(int r, int c) {
  return r * 2048 + ((((c << 1) ^ ((r & 7) << 4))) >> 1);
}
__device__ __forceinline__ f32x4 mfma16(bf16x8 a, bf16x8 b, f32x4 c) {
  return __builtin_amdgcn_mfma_f32_16x16x32_bf16(a, b, c, 0, 0, 0);
}

// ---------------- convert fp32 inputs -> bf16 workspace (vectorized x4) ----------------
__global__ void convert_all(
    const float* __restrict__ key, const float* __restrict__ query,
    const float* __restrict__ memory, const float* __restrict__ pos,
    const int* __restrict__ mask,
    const float* __restrict__ Wk, const float* __restrict__ Wv,
    const float* __restrict__ Wq, const float* __restrict__ Wp,
    const float* __restrict__ Wo,
    unsigned short* __restrict__ kcat, unsigned short* __restrict__ qbf,
    unsigned short* __restrict__ posb,
    unsigned short* __restrict__ wkb, unsigned short* __restrict__ wvb,
    unsigned short* __restrict__ wqb, unsigned short* __restrict__ wpb,
    unsigned short* __restrict__ wob, unsigned short* __restrict__ mkb)
{
  const int g0 = 1048576;            // kcat /4
  const int g1 = g0 + 524288;        // query
  const int g2 = g1 + 524288;        // pos
  const int g3 = g2 + 262144;        // Wk
  const int g4 = g3 + 262144;        // Wv
  const int g5 = g4 + 262144;        // Wq
  const int g6 = g5 + 262144;        // Wp
  const int g7 = g6 + 262144;        // Wo
  const int g8 = g7 + 1048576;       // mask
  for (int g = blockIdx.x * blockDim.x + threadIdx.x; g < g8;
       g += gridDim.x * blockDim.x) {
    const float* src = nullptr;
    unsigned short* dst = nullptr;
    int i;
    if (g < g0) {
      i = g * 4;
      int b = i >> 21, r = i & ((1 << 21) - 1);
      int t = r >> 10, c = r & 1023;
      src = (t < 1024) ? memory + ((size_t)b << 20) + (t << 10) + c
                       : key + ((size_t)b << 20) + ((t - 1024) << 10) + c;
      dst = kcat + i;
    } else if (g < g1) { i = (g - g0) * 4; src = query + i; dst = qbf + i; }
    else if (g < g2)   { i = (g - g1) * 4; src = pos + i;   dst = posb + i; }
    else if (g < g3)   { i = (g - g2) * 4; src = Wk + i;    dst = wkb + i; }
    else if (g < g4)   { i = (g - g3) * 4; src = Wv + i;    dst = wvb + i; }
    else if (g < g5)   { i = (g - g4) * 4; src = Wq + i;    dst = wqb + i; }
    else if (g < g6)   { i = (g - g5) * 4; src = Wp + i;    dst = wpb + i; }
    else if (g < g7)   { i = (g - g6) * 4; src = Wo + i;    dst = wob + i; }
    else {
      i = (g - g7) * 4;
      const int4 mv = *(const int4*)(mask + i);
      const unsigned int nm = f2bf(-1e30f);
      uint2 o;
      o.x = (mv.x ? 0u : nm) | ((mv.y ? 0u : nm) << 16);
      o.y = (mv.z ? 0u : nm) | ((mv.w ? 0u : nm) << 16);
      *(uint2*)(mkb + i) = o;
      continue;
    }
    const float4 v = *(const float4*)src;
    uint2 o;
    o.x = cvtpk(v.x, v.y);
    o.y = cvtpk(v.z, v.w);
    *(uint2*)dst = o;
  }
}

// ------------- shared GEMM core: 128x128 bf16 tile, acc in regs -------------
#define GEMM_CORE(Aptr, Bptr) \
  f32x4 acc[4][4] = {}; \
  { \
    bf16x8 ra0 = *(const bf16x8*)Ap0; \
    bf16x8 ra1 = *(const bf16x8*)Ap1; \
    bf16x8 rb0 = *(const bf16x8*)Bp0; \
    bf16x8 rb1 = *(const bf16x8*)Bp1; \
    for (int kt = 0; kt < 32; ++kt) { \
      *(bf16x8*)(sA + swA0) = ra0; \
      *(bf16x8*)(sA + swA1) = ra1; \
      *(bf16x8*)(sB + swA0) = rb0; \
      *(bf16x8*)(sB + swA1) = rb1; \
      __syncthreads(); \
      if (kt + 1 < 32) { \
        const int o = (kt + 1) * 32; \
        ra0 = *(const bf16x8*)(Ap0 + o); \
        ra1 = *(const bf16x8*)(Ap1 + o); \
        rb0 = *(const bf16x8*)(Bp0 + o); \
        rb1 = *(const bf16x8*)(Bp1 + o); \
      } \
      bf16x8 af[4], bfr[4]; \
      _Pragma("unroll") \
      for (int mi = 0; mi < 4; ++mi) { \
        int row = wm + mi * 16 + l15; \
        af[mi] = *(const bf16x8*)(sA + row * 32 + ((l4 ^ ((row >> 1) & 3)) * 8)); \
      } \
      _Pragma("unroll") \
      for (int ni = 0; ni < 4; ++ni) { \
        int row = wn + ni * 16 + l15; \
        bfr[ni] = *(const bf16x8*)(sB + row * 32 + ((l4 ^ ((row >> 1) & 3)) * 8)); \
      } \
      _Pragma("unroll") \
      for (int mi = 0; mi < 4; ++mi) \
        _Pragma("unroll") \
        for (int ni = 0; ni < 4; ++ni) \
          acc[mi][ni] = mfma16(af[mi], bfr[ni], acc[mi][ni]); \
      __syncthreads(); \
    } \
  }

#define GEMM_PREAMBLE(Asrc, Bsrc) \
  constexpr int K = 1024; \
  __shared__ unsigned short sA[128 * 32]; \
  __shared__ unsigned short sB[128 * 32]; \
  const int tid = threadIdx.x; \
  const int lane = tid & 63; \
  const int wid = tid >> 6; \
  const int wm = (wid >> 1) * 64, wn = (wid & 1) * 64; \
  const int bm = blockIdx.y * 128, bn = blockIdx.x * 128; \
  const int l15 = lane & 15, l4 = lane >> 4; \
  const int c0 = tid, c1 = tid + 256; \
  const int am0 = c0 >> 2, as0 = c0 & 3; \
  const int am1 = c1 >> 2, as1 = c1 & 3; \
  const unsigned short* Ap0 = Asrc + (size_t)(bm + am0) * K + as0 * 8; \
  const unsigned short* Ap1 = Asrc + (size_t)(bm + am1) * K + as1 * 8; \
  const unsigned short* Bp0 = Bsrc + (size_t)(bn + am0) * K + as0 * 8; \
  const unsigned short* Bp1 = Bsrc + (size_t)(bn + am1) * K + as1 * 8; \
  const int swA0 = am0 * 32 + ((as0 ^ ((am0 >> 1) & 3)) * 8); \
  const int swA1 = am1 * 32 + ((as1 ^ ((am1 >> 1) & 3)) * 8);

// K+V projection in ONE launch: A = kcat [4096,1024], B = [Wk;Wv] [2048,1024]
__global__ __launch_bounds__(256, 2) void gemm_kv(
    const unsigned short* __restrict__ A, const unsigned short* __restrict__ Bw,
    const float* __restrict__ bk, const float* __restrict__ bv,
    unsigned short* __restrict__ kpk, unsigned short* __restrict__ vpk)
{
  GEMM_PREAMBLE(A, Bw)
  GEMM_CORE(A, Bw)
  const bool isK = bn < 1024;
  #pragma unroll
  for (int mi = 0; mi < 4; ++mi) {
    #pragma unroll
    for (int ni = 0; ni < 4; ++ni) {
      const int col = bn + wn + ni * 16 + l15;
      const int cc = col & 1023;
      const float bval = isK ? bk[cc] : bv[cc];
      #pragma unroll
      for (int j = 0; j < 4; ++j) {
        const int row = bm + wm + mi * 16 + l4 * 4 + j;
        const float cv = acc[mi][ni][j] + bval;
        const int bI = row >> 11;
        const int t = row & 2047;
        const int bh2 = bI * NH + (cc >> 6);
        if (isK) {
          const size_t o = ((((size_t)bh2 * 128 + (t >> 4)) * 8 +
                            ((cc & 63) >> 3)) * 16 + (t & 15)) * 8 + (cc & 7);
          kpk[o] = f2bf(cv);
        } else {
          const int dk = cc & 63;
          const size_t o = (((((size_t)bh2 * 4 + (dk >> 4)) * 64 + (t >> 5)) * 4 +
                            ((t >> 3) & 3)) * 16 + (dk & 15)) * 8 + (t & 7);
          vpk[o] = f2bf(cv);
        }
      }
    }
  }
}

// Q (+u,+v) and POS projections in one launch via blockIdx.z
__global__ __launch_bounds__(256, 2) void gemm_qp(
    const unsigned short* __restrict__ qry, const unsigned short* __restrict__ posb,
    const unsigned short* __restrict__ wqb, const unsigned short* __restrict__ wpb,
    const float* __restrict__ bq, const float* __restrict__ bp,
    const float* __restrict__ uvec, const float* __restrict__ vvec,
    unsigned short* __restrict__ qupk, unsigned short* __restrict__ qvpk,
    unsigned short* __restrict__ ppk)
{
  const bool isQ = blockIdx.z == 0;
  const unsigned short* A  = isQ ? qry : posb;
  const unsigned short* Bw = isQ ? wqb : wpb;
  GEMM_PREAMBLE(A, Bw)
  GEMM_CORE(A, Bw)
  #pragma unroll
  for (int mi = 0; mi < 4; ++mi) {
    #pragma unroll
    for (int ni = 0; ni < 4; ++ni) {
      const int col = bn + wn + ni * 16 + l15;
      #pragma unroll
      for (int j = 0; j < 4; ++j) {
        const int row = bm + wm + mi * 16 + l4 * 4 + j;
        if (isQ) {
          const float cv = acc[mi][ni][j] + bq[col];
          const int bI = row >> 10;
          const int t = row & 1023;
          const int bh2 = bI * NH + (col >> 6);
          const size_t o = ((((size_t)bh2 * 64 + (t >> 4)) * 8 +
                            ((col & 63) >> 3)) * 16 + (t & 15)) * 8 + (col & 7);
          qupk[o] = f2bf(cv + uvec[col]);
          qvpk[o] = f2bf(cv + vvec[col]);
        } else {
          const float cv = acc[mi][ni][j] + bp[col];
          const int t = row;                  // single 2048-row batch
          const int h2 = col >> 6;
          const size_t o = ((((size_t)h2 * 128 + (t >> 4)) * 8 +
                            ((col & 63) >> 3)) * 16 + (t & 15)) * 8 + (col & 7);
          ppk[o] = f2bf(cv);
        }
      }
    }
  }
}

// final projection: fp32 row-major out
__global__ __launch_bounds__(256, 2) void gemm_out(
    const unsigned short* __restrict__ A, const unsigned short* __restrict__ Bw,
    const float* __restrict__ bias, float* __restrict__ outf)
{
  GEMM_PREAMBLE(A, Bw)
  GEMM_CORE(A, Bw)
  #pragma unroll
  for (int mi = 0; mi < 4; ++mi) {
    #pragma unroll
    for (int ni = 0; ni < 4; ++ni) {
      const int col = bn + wn + ni * 16 + l15;
      const float bval = bias[col];
      #pragma unroll
      for (int j = 0; j < 4; ++j) {
        const int row = bm + wm + mi * 16 + l4 * 4 + j;
        outf[(size_t)row * 1024 + col] = acc[mi][ni][j] + bval;
      }
    }
  }
}

// ---------------- fused scores + rel_shift + softmax + aw write + PV ----------------
// 16 q-rows/block, 16 waves (1024 thr), 2 blocks/CU -> 32 waves/CU (100% occ;
// R10 was 14/32 at 512 thr and latency-bound with VALU 30%/HBM 23%/MFMA 6%).
// LDS: sbd 64K + spv 12K + sred 1K = 78.8K; x2 = 157.7K <= 160K.
// __launch_bounds__(1024,8) pins the 64-VGPR budget (current need: 52).
__global__ __launch_bounds__(1024, 8) void attn_fused(
    const unsigned short* __restrict__ qupk, const unsigned short* __restrict__ qvpk,
    const unsigned short* __restrict__ kpk, const unsigned short* __restrict__ ppk,
    const unsigned short* __restrict__ vpk, const unsigned short* __restrict__ mkb,
    float* __restrict__ awout, unsigned short* __restrict__ cvb)
{
  __shared__ unsigned short sbd[16 * 2048];   // 64 KB: BD -> p (bf16)
  __shared__ float sred0[16][16];             // per-wave row sums
  __shared__ float spv[3][4][16][16];         // split-K partials (kh=1..3)
  const int tid = threadIdx.x;
  const int lane = tid & 63;
  const int w = tid >> 6;                      // 0..15
  const int l15 = lane & 15, l4 = lane >> 4;

  const int wg = blockIdx.x;                   // XCD-grouped, bh interleaved
  const int xcd = wg & 7, idx = wg >> 3;
  const int bh = xcd * 4 + (idx & 3);
  const int tI = idx >> 2;                     // 0..63
  const int I0 = tI * 16;
  const int b = bh >> 4, h = bh & 15;

  // ---- P1: BD via MFMA, scatter-written through the rel_shift mapping ----
  {
    const unsigned short* qvt = qvpk + ((size_t)bh * 64 + tI) * 1024;
    bf16x8 a0 = *(const bf16x8*)(qvt + l4 * 128 + l15 * 8);
    bf16x8 a1 = *(const bf16x8*)(qvt + (4 + l4) * 128 + l15 * 8);
    const unsigned short* ppk_h = ppk + (size_t)h * 131072;
    #pragma unroll 8
    for (int nj = 0; nj < 8; ++nj) {
      const int tile = w * 8 + nj;             // 0..127
      const unsigned short* pt = ppk_h + (size_t)tile * 1024;
      bf16x8 b0 = *(const bf16x8*)(pt + l4 * 128 + l15 * 8);
      bf16x8 b1 = *(const bf16x8*)(pt + (4 + l4) * 128 + l15 * 8);
      f32x4 c = {0.f, 0.f, 0.f, 0.f};
      c = mfma16(a0, b0, c);
      c = mfma16(a1, b1, c);
      const int jj = tile * 16 + l15;
      #pragma unroll
      for (int j = 0; j < 4; ++j) {
        const int rl = l4 * 4 + j;
        const int r = I0 + rl;
        int dst, jp;
        if (jj >= 1023 - r) { dst = rl;     jp = jj + r - 1023; }  // tail part
        else                { dst = rl - 1; jp = jj + r + 1025; }  // wrap part
        if (dst >= 0) sbd[swz(dst, jp)] = f2bf(c[j]);
      }
    }
    // extra BD row (I0+16) feeds last output row's wrap region (jj < 1024)
    if (I0 <= 1006 && w < 8) {
      const unsigned short* qvt2 = qvpk + ((size_t)bh * 64 + tI + 1) * 1024;
      bf16x8 a0e = *(const bf16x8*)(qvt2 + l4 * 128 + l15 * 8);
      bf16x8 a1e = *(const bf16x8*)(qvt2 + (4 + l4) * 128 + l15 * 8);
      #pragma unroll 8
      for (int nj = 0; nj < 8; ++nj) {
        const int tile = w * 8 + nj;           // 0..63
        const unsigned short* pt = ppk_h + (size_t)tile * 1024;
        bf16x8 b0 = *(const bf16x8*)(pt + l4 * 128 + l15 * 8);
        bf16x8 b1 = *(const bf16x8*)(pt + (4 + l4) * 128 + l15 * 8);
        f32x4 c = {0.f, 0.f, 0.f, 0.f};
        c = mfma16(a0e, b0, c);
        c = mfma16(a1e, b1, c);
        const int jj = tile * 16 + l15;
        if (l4 == 0 && jj <= 1006 - I0)
          sbd[swz(15, jj + I0 + 1041)] = f2bf(c[0]);
      }
    }
    if (tid < 16) {   // the zero column injected by the pad/reshape trick
      const int jp = I0 + tid + 1025;
      if (jp < 2048) sbd[swz(tid, jp)] = 0;
    }
  }
  __syncthreads();

  // ---- P2: AC (swapped MFMA) + BD + mask + exp -> p in place, row sums ----
  {
    const unsigned short* qut = qupk + ((size_t)bh * 64 + tI) * 1024;
    bf16x8 a0 = *(const bf16x8*)(qut + l4 * 128 + l15 * 8);
    bf16x8 a1 = *(const bf16x8*)(qut + (4 + l4) * 128 + l15 * 8);
    const unsigned short* kpk_b = kpk + (size_t)bh * 131072;
    const unsigned short* mrow = mkb + ((size_t)b * QL + I0 + l15) * TTOT;
    const int rowbyte = l15 * 4096;            // this thread's q-row = l15
    const int sws = (l15 & 7) << 4;
    float sm = 0.f;
    #pragma unroll 8
    for (int nj = 0; nj < 8; ++nj) {
      const int tile = w * 8 + nj;             // 0..127
      const unsigned short* kt = kpk_b + (size_t)tile * 1024;
      bf16x8 b0 = *(const bf16x8*)(kt + l4 * 128 + l15 * 8);
      bf16x8 b1 = *(const bf16x8*)(kt + (4 + l4) * 128 + l15 * 8);
      f32x4 c = {0.f, 0.f, 0.f, 0.f};
      c = mfma16(b0, a0, c);                   // swapped: rows=K pos, cols=q rows
      c = mfma16(b1, a1, c);
      const int jp0 = tile * 16 + l4 * 4;
      char* sp = (char*)sbd + rowbyte + ((jp0 * 2) ^ sws);
      const bf16x4 bd4 = *(const bf16x4*)sp;
      const bf16x4 m4 = *(const bf16x4*)(mrow + jp0);
      bf16x4 pw;
      #pragma unroll
      for (int j = 0; j < 4; ++j) {
        const float s = (c[j] + bf2f((unsigned short)bd4[j])) * 0.125f +
                        bf2f((unsigned short)m4[j]);
        const float p = __expf(s);
        sm += p;
        pw[j] = (short)f2bf(p);
      }
      *(bf16x4*)sp = pw;
    }
    sm += __shfl_xor(sm, 16, 64);
    sm += __shfl_xor(sm, 32, 64);
    if (l4 == 0) sred0[w][l15] = sm;
  }
  __syncthreads();

  // ---- P5a: aw fp32 write, normalized on the fly (one row per wave) ----
  {
    const int r = w;                           // 0..15
    float den = sred0[0][r];
    #pragma unroll
    for (int ww = 1; ww < 16; ++ww) den += sred0[ww][r];
    const float rinv = 1.0f / den;
    float* awb = awout + ((size_t)bh * QL + I0 + r) * TTOT;
    const int sws = (r & 7) << 4;
    #pragma unroll
    for (int q = 0; q < 4; ++q) {
      const int X = q * 1024 + lane * 16;               // true column byte
      bf16x8 vv = *(const bf16x8*)((const char*)sbd + r * 4096 + (X ^ sws));
      f32x4 lo, hi;
      #pragma unroll
      for (int k = 0; k < 4; ++k) {
        lo[k] = bf2f((unsigned short)vv[k]) * rinv;
        hi[k] = bf2f((unsigned short)vv[k + 4]) * rinv;
      }
      float* dp = awb + (X >> 1);                       // unswizzled destination
      *(f32x4*)dp = lo;
      *(f32x4*)(dp + 4) = hi;
    }
  }

  // ---- P5b: PV on p (packed V), 4-way split-K across waves; normalize last ----
  {
    const int dc = w & 3, kh = w >> 2;         // kh 0..3
    const unsigned short* vb = vpk + ((size_t)(bh * 4 + dc) * 64) * 512;
    const int sws = (l15 & 7) << 4;
    const int rowbyte = l15 * 4096;
    f32x4 pv = {0.f, 0.f, 0.f, 0.f};
    #pragma unroll 8
    for (int ks = kh * 16; ks < kh * 16 + 16; ++ks) {
      bf16x8 a = *(const bf16x8*)((const char*)sbd +
                  (rowbyte + ((ks * 64 + l4 * 16) ^ sws)));
      bf16x8 vvf = *(const bf16x8*)(vb + ks * 512 + lane * 8);
      pv = mfma16(a, vvf, pv);
    }
    if (kh) {
      #pragma unroll
      for (int j = 0; j < 4; ++j) spv[kh - 1][dc][l4 * 4 + j][l15] = pv[j];
    }
    __syncthreads();
    if (!kh) {
      const size_t obase = ((size_t)b * QL + I0 + l4 * 4) * 1024 + h * 64 + dc * 16 + l15;
      #pragma unroll
      for (int j = 0; j < 4; ++j) {
        const int rl = l4 * 4 + j;
        float den = sred0[0][rl];
        #pragma unroll
        for (int ww = 1; ww < 16; ++ww) den += sred0[ww][rl];
        const float o = (pv[j] + spv[0][dc][rl][l15] + spv[1][dc][rl][l15] +
                         spv[2][dc][rl][l15]) / den;
        cvb[obase + (size_t)j * 1024] = f2bf(o);
      }
    }
  }
}

extern "C" void kernel_launch(void* const* d_in, const int* in_sizes, int n_in,
                              void* d_out, int out_size, void* d_ws, size_t ws_size,
                              hipStream_t stream) {
  (void)in_sizes; (void)n_in; (void)out_size; (void)ws_size;
  const float* key    = (const float*)d_in[0];
  const float* query  = (const float*)d_in[1];
  const float* memory = (const float*)d_in[2];
  const float* pos    = (const float*)d_in[3];
  const int*   mask   = (const int*)d_in[4];
  const float* u      = (const float*)d_in[5];
  const float* v      = (const float*)d_in[6];
  const float* Wk     = (const float*)d_in[7];
  const float* bk     = (const float*)d_in[8];
  const float* Wv     = (const float*)d_in[9];
  const float* bv     = (const float*)d_in[10];
  const float* Wq     = (const float*)d_in[11];
  const float* bq     = (const float*)d_in[12];
  const float* Wp     = (const float*)d_in[13];
  const float* bp     = (const float*)d_in[14];
  const float* Wo     = (const float*)d_in[15];
  const float* bo     = (const float*)d_in[16];

  float* outCV = (float*)d_out;
  float* outAW = outCV + 2097152;

  char* ws = (char*)d_ws;
  const size_t MB = (size_t)1 << 20;
  unsigned short* kpk  = (unsigned short*)(ws + 0);        // packed K     8MB
  unsigned short* vpk  = (unsigned short*)(ws + 8 * MB);   // packed V     8MB
  unsigned short* qupk = (unsigned short*)(ws + 16 * MB);  // packed q+u   4MB
  unsigned short* qvpk = (unsigned short*)(ws + 20 * MB);  // packed q+v   4MB
  unsigned short* ppk  = (unsigned short*)(ws + 24 * MB);  // packed pos   4MB
  unsigned short* cvb  = (unsigned short*)(ws + 28 * MB);  // [b*Q][1024]  4MB
  unsigned short* kcat = (unsigned short*)(ws + 32 * MB);  // [b][t][1024] 8MB
  unsigned short* qry  = (unsigned short*)(ws + 40 * MB);  // 4MB
  unsigned short* posb = (unsigned short*)(ws + 44 * MB);  // 4MB
  unsigned short* wkb  = (unsigned short*)(ws + 48 * MB);  // 2MB (contig with wvb!)
  unsigned short* wvb  = (unsigned short*)(ws + 50 * MB);  // 2MB
  unsigned short* wqb  = (unsigned short*)(ws + 52 * MB);
  unsigned short* wpb  = (unsigned short*)(ws + 54 * MB);
  unsigned short* wob  = (unsigned short*)(ws + 56 * MB);
  unsigned short* mkb  = (unsigned short*)(ws + 58 * MB);  // row-major mask 8MB

  convert_all<<<2048, 256, 0, stream>>>(key, query, memory, pos, mask,
      Wk, Wv, Wq, Wp, Wo, kcat, qry, posb, wkb, wvb, wqb, wpb, wob, mkb);

  // K+V in one launch (B = [Wk;Wv] contiguous), Q+POS in one launch (z)
  gemm_kv<<<dim3(16, 32), 256, 0, stream>>>(kcat, wkb, bk, bv, kpk, vpk);
  gemm_qp<<<dim3(8, 16, 2), 256, 0, stream>>>(qry, posb, wqb, wpb, bq, bp,
      u, v, qupk, qvpk, ppk);

  attn_fused<<<2048, 1024, 0, stream>>>(qupk, qvpk, kpk, ppk, vpk, mkb,
      outAW, cvb);

  gemm_out<<<dim3(8, 16), 256, 0, stream>>>(cvb, wob, bo, outCV);
}

// Round 12
// 256.522 us; speedup vs baseline: 1.3005x; 1.3005x over previous
//
#include <hip/hip_runtime.h>

using bf16x8 = __attribute__((ext_vector_type(8))) short;
using bf16x4 = __attribute__((ext_vector_type(4))) short;
using f32x4  = __attribute__((ext_vector_type(4))) float;

#define NH    16
#define DKH   64
#define TTOT  2048
#define QL    1024

__device__ __forceinline__ float bf2f(unsigned short u) {
  union { unsigned int i; float f; } c; c.i = ((unsigned int)u) << 16; return c.f;
}
__device__ __forceinline__ unsigned short f2bf(float f) {
  union { float f; unsigned int i; } c; c.f = f;
  unsigned int x = c.i;
  x += 0x7fffu + ((x >> 16) & 1u);
  return (unsigned short)(x >> 16);
}
// HW packed f32->bf16. ORDER-INSENSITIVE uses only (R9 post-mortem):
// applied identically to both GEMM operands, a pairwise K-permutation cancels.
__device__ __forceinline__ unsigned int cvtpk(float lo, float hi) {
  unsigned int r;
  asm("v_cvt_pk_bf16_f32 %0, %1, %2" : "=v"(r) : "v"(lo), "v"(hi));
  return r;
}
// XOR swizzle inside each row (byte bits 4..6 ^= row&7) for 16x2048 bf16 LDS rows
__device__ __forceinline__ int swz(int r, int c) {
  return r * 2048 + ((((c << 1) ^ ((r & 7) << 4))) >> 1);
}
__device__ __forceinline__ f32x4 mfma16(bf16x8 a, bf16x8 b, f32x4 c) {
  return __builtin_amdgcn_mfma_f32_16x16x32_bf16(a, b, c, 0, 0, 0);
}

// ---------------- convert fp32 inputs -> bf16 workspace (vectorized x4) ----------------
__global__ void convert_all(
    const float* __restrict__ key, const float* __restrict__ query,
    const float* __restrict__ memory, const float* __restrict__ pos,
    const int* __restrict__ mask,
    const float* __restrict__ Wk, const float* __restrict__ Wv,
    const float* __restrict__ Wq, const float* __restrict__ Wp,
    const float* __restrict__ Wo,
    unsigned short* __restrict__ kcat, unsigned short* __restrict__ qbf,
    unsigned short* __restrict__ posb,
    unsigned short* __restrict__ wkb, unsigned short* __restrict__ wvb,
    unsigned short* __restrict__ wqb, unsigned short* __restrict__ wpb,
    unsigned short* __restrict__ wob, unsigned short* __restrict__ mkb)
{
  const int g0 = 1048576;            // kcat /4
  const int g1 = g0 + 524288;        // query
  const int g2 = g1 + 524288;        // pos
  const int g3 = g2 + 262144;        // Wk
  const int g4 = g3 + 262144;        // Wv
  const int g5 = g4 + 262144;        // Wq
  const int g6 = g5 + 262144;        // Wp
  const int g7 = g6 + 262144;        // Wo
  const int g8 = g7 + 1048576;       // mask
  for (int g = blockIdx.x * blockDim.x + threadIdx.x; g < g8;
       g += gridDim.x * blockDim.x) {
    const float* src = nullptr;
    unsigned short* dst = nullptr;
    int i;
    if (g < g0) {
      i = g * 4;
      int b = i >> 21, r = i & ((1 << 21) - 1);
      int t = r >> 10, c = r & 1023;
      src = (t < 1024) ? memory + ((size_t)b << 20) + (t << 10) + c
                       : key + ((size_t)b << 20) + ((t - 1024) << 10) + c;
      dst = kcat + i;
    } else if (g < g1) { i = (g - g0) * 4; src = query + i; dst = qbf + i; }
    else if (g < g2)   { i = (g - g1) * 4; src = pos + i;   dst = posb + i; }
    else if (g < g3)   { i = (g - g2) * 4; src = Wk + i;    dst = wkb + i; }
    else if (g < g4)   { i = (g - g3) * 4; src = Wv + i;    dst = wvb + i; }
    else if (g < g5)   { i = (g - g4) * 4; src = Wq + i;    dst = wqb + i; }
    else if (g < g6)   { i = (g - g5) * 4; src = Wp + i;    dst = wpb + i; }
    else if (g < g7)   { i = (g - g6) * 4; src = Wo + i;    dst = wob + i; }
    else {
      i = (g - g7) * 4;
      const int4 mv = *(const int4*)(mask + i);
      const unsigned int nm = f2bf(-1e30f);
      uint2 o;
      o.x = (mv.x ? 0u : nm) | ((mv.y ? 0u : nm) << 16);
      o.y = (mv.z ? 0u : nm) | ((mv.w ? 0u : nm) << 16);
      *(uint2*)(mkb + i) = o;
      continue;
    }
    const float4 v = *(const float4*)src;
    uint2 o;
    o.x = cvtpk(v.x, v.y);
    o.y = cvtpk(v.z, v.w);
    *(uint2*)dst = o;
  }
}

// ------------- shared GEMM core: 128x128 bf16 tile, acc in regs -------------
#define GEMM_CORE(Aptr, Bptr) \
  f32x4 acc[4][4] = {}; \
  { \
    bf16x8 ra0 = *(const bf16x8*)Ap0; \
    bf16x8 ra1 = *(const bf16x8*)Ap1; \
    bf16x8 rb0 = *(const bf16x8*)Bp0; \
    bf16x8 rb1 = *(const bf16x8*)Bp1; \
    for (int kt = 0; kt < 32; ++kt) { \
      *(bf16x8*)(sA + swA0) = ra0; \
      *(bf16x8*)(sA + swA1) = ra1; \
      *(bf16x8*)(sB + swA0) = rb0; \
      *(bf16x8*)(sB + swA1) = rb1; \
      __syncthreads(); \
      if (kt + 1 < 32) { \
        const int o = (kt + 1) * 32; \
        ra0 = *(const bf16x8*)(Ap0 + o); \
        ra1 = *(const bf16x8*)(Ap1 + o); \
        rb0 = *(const bf16x8*)(Bp0 + o); \
        rb1 = *(const bf16x8*)(Bp1 + o); \
      } \
      bf16x8 af[4], bfr[4]; \
      _Pragma("unroll") \
      for (int mi = 0; mi < 4; ++mi) { \
        int row = wm + mi * 16 + l15; \
        af[mi] = *(const bf16x8*)(sA + row * 32 + ((l4 ^ ((row >> 1) & 3)) * 8)); \
      } \
      _Pragma("unroll") \
      for (int ni = 0; ni < 4; ++ni) { \
        int row = wn + ni * 16 + l15; \
        bfr[ni] = *(const bf16x8*)(sB + row * 32 + ((l4 ^ ((row >> 1) & 3)) * 8)); \
      } \
      _Pragma("unroll") \
      for (int mi = 0; mi < 4; ++mi) \
        _Pragma("unroll") \
        for (int ni = 0; ni < 4; ++ni) \
          acc[mi][ni] = mfma16(af[mi], bfr[ni], acc[mi][ni]); \
      __syncthreads(); \
    } \
  }

#define GEMM_PREAMBLE(Asrc, Bsrc) \
  constexpr int K = 1024; \
  __shared__ unsigned short sA[128 * 32]; \
  __shared__ unsigned short sB[128 * 32]; \
  const int tid = threadIdx.x; \
  const int lane = tid & 63; \
  const int wid = tid >> 6; \
  const int wm = (wid >> 1) * 64, wn = (wid & 1) * 64; \
  const int bm = blockIdx.y * 128, bn = blockIdx.x * 128; \
  const int l15 = lane & 15, l4 = lane >> 4; \
  const int c0 = tid, c1 = tid + 256; \
  const int am0 = c0 >> 2, as0 = c0 & 3; \
  const int am1 = c1 >> 2, as1 = c1 & 3; \
  const unsigned short* Ap0 = Asrc + (size_t)(bm + am0) * K + as0 * 8; \
  const unsigned short* Ap1 = Asrc + (size_t)(bm + am1) * K + as1 * 8; \
  const unsigned short* Bp0 = Bsrc + (size_t)(bn + am0) * K + as0 * 8; \
  const unsigned short* Bp1 = Bsrc + (size_t)(bn + am1) * K + as1 * 8; \
  const int swA0 = am0 * 32 + ((as0 ^ ((am0 >> 1) & 3)) * 8); \
  const int swA1 = am1 * 32 + ((as1 ^ ((am1 >> 1) & 3)) * 8);

// K+V projection in ONE launch: A = kcat [4096,1024], B = [Wk;Wv] [2048,1024]
__global__ __launch_bounds__(256, 2) void gemm_kv(
    const unsigned short* __restrict__ A, const unsigned short* __restrict__ Bw,
    const float* __restrict__ bk, const float* __restrict__ bv,
    unsigned short* __restrict__ kpk, unsigned short* __restrict__ vpk)
{
  GEMM_PREAMBLE(A, Bw)
  GEMM_CORE(A, Bw)
  const bool isK = bn < 1024;
  #pragma unroll
  for (int mi = 0; mi < 4; ++mi) {
    #pragma unroll
    for (int ni = 0; ni < 4; ++ni) {
      const int col = bn + wn + ni * 16 + l15;
      const int cc = col & 1023;
      const float bval = isK ? bk[cc] : bv[cc];
      #pragma unroll
      for (int j = 0; j < 4; ++j) {
        const int row = bm + wm + mi * 16 + l4 * 4 + j;
        const float cv = acc[mi][ni][j] + bval;
        const int bI = row >> 11;
        const int t = row & 2047;
        const int bh2 = bI * NH + (cc >> 6);
        if (isK) {
          const size_t o = ((((size_t)bh2 * 128 + (t >> 4)) * 8 +
                            ((cc & 63) >> 3)) * 16 + (t & 15)) * 8 + (cc & 7);
          kpk[o] = f2bf(cv);
        } else {
          const int dk = cc & 63;
          const size_t o = (((((size_t)bh2 * 4 + (dk >> 4)) * 64 + (t >> 5)) * 4 +
                            ((t >> 3) & 3)) * 16 + (dk & 15)) * 8 + (t & 7);
          vpk[o] = f2bf(cv);
        }
      }
    }
  }
}

// Q (+u,+v) and POS projections in one launch via blockIdx.z
__global__ __launch_bounds__(256, 2) void gemm_qp(
    const unsigned short* __restrict__ qry, const unsigned short* __restrict__ posb,
    const unsigned short* __restrict__ wqb, const unsigned short* __restrict__ wpb,
    const float* __restrict__ bq, const float* __restrict__ bp,
    const float* __restrict__ uvec, const float* __restrict__ vvec,
    unsigned short* __restrict__ qupk, unsigned short* __restrict__ qvpk,
    unsigned short* __restrict__ ppk)
{
  const bool isQ = blockIdx.z == 0;
  const unsigned short* A  = isQ ? qry : posb;
  const unsigned short* Bw = isQ ? wqb : wpb;
  GEMM_PREAMBLE(A, Bw)
  GEMM_CORE(A, Bw)
  #pragma unroll
  for (int mi = 0; mi < 4; ++mi) {
    #pragma unroll
    for (int ni = 0; ni < 4; ++ni) {
      const int col = bn + wn + ni * 16 + l15;
      #pragma unroll
      for (int j = 0; j < 4; ++j) {
        const int row = bm + wm + mi * 16 + l4 * 4 + j;
        if (isQ) {
          const float cv = acc[mi][ni][j] + bq[col];
          const int bI = row >> 10;
          const int t = row & 1023;
          const int bh2 = bI * NH + (col >> 6);
          const size_t o = ((((size_t)bh2 * 64 + (t >> 4)) * 8 +
                            ((col & 63) >> 3)) * 16 + (t & 15)) * 8 + (col & 7);
          qupk[o] = f2bf(cv + uvec[col]);
          qvpk[o] = f2bf(cv + vvec[col]);
        } else {
          const float cv = acc[mi][ni][j] + bp[col];
          const int t = row;                  // single 2048-row batch
          const int h2 = col >> 6;
          const size_t o = ((((size_t)h2 * 128 + (t >> 4)) * 8 +
                            ((col & 63) >> 3)) * 16 + (t & 15)) * 8 + (col & 7);
          ppk[o] = f2bf(cv);
        }
      }
    }
  }
}

// final projection: fp32 row-major out
__global__ __launch_bounds__(256, 2) void gemm_out(
    const unsigned short* __restrict__ A, const unsigned short* __restrict__ Bw,
    const float* __restrict__ bias, float* __restrict__ outf)
{
  GEMM_PREAMBLE(A, Bw)
  GEMM_CORE(A, Bw)
  #pragma unroll
  for (int mi = 0; mi < 4; ++mi) {
    #pragma unroll
    for (int ni = 0; ni < 4; ++ni) {
      const int col = bn + wn + ni * 16 + l15;
      const float bval = bias[col];
      #pragma unroll
      for (int j = 0; j < 4; ++j) {
        const int row = bm + wm + mi * 16 + l4 * 4 + j;
        outf[(size_t)row * 1024 + col] = acc[mi][ni][j] + bval;
      }
    }
  }
}

// ---------------- fused scores + rel_shift + softmax + aw write + PV ----------------
// 16 q-rows/block, 16 waves (1024 thr), 2 blocks/CU -> 32 waves/CU.
// __launch_bounds__(1024,8) -> hard 64-VGPR budget (512-reg file / 8 waves).
// R11 spilled because unroll-8 fully unrolled the 8-iter loops and the
// scheduler hoisted 8 iterations of operand loads (>100 VGPR peak). Unroll 2
// caps loads-in-flight at ~32 VGPR; 32 waves/CU provide the latency hiding.
__global__ __launch_bounds__(1024, 8) void attn_fused(
    const unsigned short* __restrict__ qupk, const unsigned short* __restrict__ qvpk,
    const unsigned short* __restrict__ kpk, const unsigned short* __restrict__ ppk,
    const unsigned short* __restrict__ vpk, const unsigned short* __restrict__ mkb,
    float* __restrict__ awout, unsigned short* __restrict__ cvb)
{
  __shared__ unsigned short sbd[16 * 2048];   // 64 KB: BD -> p (bf16)
  __shared__ float sred0[16][16];             // per-wave row sums
  __shared__ float spv[3][4][16][16];         // split-K partials (kh=1..3)
  const int tid = threadIdx.x;
  const int lane = tid & 63;
  const int w = tid >> 6;                      // 0..15
  const int l15 = lane & 15, l4 = lane >> 4;

  const int wg = blockIdx.x;                   // XCD-grouped, bh interleaved
  const int xcd = wg & 7, idx = wg >> 3;
  const int bh = xcd * 4 + (idx & 3);
  const int tI = idx >> 2;                     // 0..63
  const int I0 = tI * 16;
  const int b = bh >> 4, h = bh & 15;

  // ---- P1: BD via MFMA, scatter-written through the rel_shift mapping ----
  {
    const unsigned short* qvt = qvpk + ((size_t)bh * 64 + tI) * 1024;
    bf16x8 a0 = *(const bf16x8*)(qvt + l4 * 128 + l15 * 8);
    bf16x8 a1 = *(const bf16x8*)(qvt + (4 + l4) * 128 + l15 * 8);
    const unsigned short* ppk_h = ppk + (size_t)h * 131072;
    #pragma unroll 2
    for (int nj = 0; nj < 8; ++nj) {
      const int tile = w * 8 + nj;             // 0..127
      const unsigned short* pt = ppk_h + (size_t)tile * 1024;
      bf16x8 b0 = *(const bf16x8*)(pt + l4 * 128 + l15 * 8);
      bf16x8 b1 = *(const bf16x8*)(pt + (4 + l4) * 128 + l15 * 8);
      f32x4 c = {0.f, 0.f, 0.f, 0.f};
      c = mfma16(a0, b0, c);
      c = mfma16(a1, b1, c);
      const int jj = tile * 16 + l15;
      #pragma unroll
      for (int j = 0; j < 4; ++j) {
        const int rl = l4 * 4 + j;
        const int r = I0 + rl;
        int dst, jp;
        if (jj >= 1023 - r) { dst = rl;     jp = jj + r - 1023; }  // tail part
        else                { dst = rl - 1; jp = jj + r + 1025; }  // wrap part
        if (dst >= 0) sbd[swz(dst, jp)] = f2bf(c[j]);
      }
    }
    // extra BD row (I0+16) feeds last output row's wrap region (jj < 1024)
    if (I0 <= 1006 && w < 8) {
      const unsigned short* qvt2 = qvpk + ((size_t)bh * 64 + tI + 1) * 1024;
      bf16x8 a0e = *(const bf16x8*)(qvt2 + l4 * 128 + l15 * 8);
      bf16x8 a1e = *(const bf16x8*)(qvt2 + (4 + l4) * 128 + l15 * 8);
      #pragma unroll 2
      for (int nj = 0; nj < 8; ++nj) {
        const int tile = w * 8 + nj;           // 0..63
        const unsigned short* pt = ppk_h + (size_t)tile * 1024;
        bf16x8 b0 = *(const bf16x8*)(pt + l4 * 128 + l15 * 8);
        bf16x8 b1 = *(const bf16x8*)(pt + (4 + l4) * 128 + l15 * 8);
        f32x4 c = {0.f, 0.f, 0.f, 0.f};
        c = mfma16(a0e, b0, c);
        c = mfma16(a1e, b1, c);
        const int jj = tile * 16 + l15;
        if (l4 == 0 && jj <= 1006 - I0)
          sbd[swz(15, jj + I0 + 1041)] = f2bf(c[0]);
      }
    }
    if (tid < 16) {   // the zero column injected by the pad/reshape trick
      const int jp = I0 + tid + 1025;
      if (jp < 2048) sbd[swz(tid, jp)] = 0;
    }
  }
  __syncthreads();

  // ---- P2: AC (swapped MFMA) + BD + mask + exp -> p in place, row sums ----
  {
    const unsigned short* qut = qupk + ((size_t)bh * 64 + tI) * 1024;
    bf16x8 a0 = *(const bf16x8*)(qut + l4 * 128 + l15 * 8);
    bf16x8 a1 = *(const bf16x8*)(qut + (4 + l4) * 128 + l15 * 8);
    const unsigned short* kpk_b = kpk + (size_t)bh * 131072;
    const unsigned short* mrow = mkb + ((size_t)b * QL + I0 + l15) * TTOT;
    const int rowbyte = l15 * 4096;            // this thread's q-row = l15
    const int sws = (l15 & 7) << 4;
    float sm = 0.f;
    #pragma unroll 2
    for (int nj = 0; nj < 8; ++nj) {
      const int tile = w * 8 + nj;             // 0..127
      const unsigned short* kt = kpk_b + (size_t)tile * 1024;
      bf16x8 b0 = *(const bf16x8*)(kt + l4 * 128 + l15 * 8);
      bf16x8 b1 = *(const bf16x8*)(kt + (4 + l4) * 128 + l15 * 8);
      f32x4 c = {0.f, 0.f, 0.f, 0.f};
      c = mfma16(b0, a0, c);                   // swapped: rows=K pos, cols=q rows
      c = mfma16(b1, a1, c);
      const int jp0 = tile * 16 + l4 * 4;
      char* sp = (char*)sbd + rowbyte + ((jp0 * 2) ^ sws);
      const bf16x4 bd4 = *(const bf16x4*)sp;
      const bf16x4 m4 = *(const bf16x4*)(mrow + jp0);
      bf16x4 pw;
      #pragma unroll
      for (int j = 0; j < 4; ++j) {
        const float s = (c[j] + bf2f((unsigned short)bd4[j])) * 0.125f +
                        bf2f((unsigned short)m4[j]);
        const float p = __expf(s);
        sm += p;
        pw[j] = (short)f2bf(p);
      }
      *(bf16x4*)sp = pw;
    }
    sm += __shfl_xor(sm, 16, 64);
    sm += __shfl_xor(sm, 32, 64);
    if (l4 == 0) sred0[w][l15] = sm;
  }
  __syncthreads();

  // ---- P5a: aw fp32 write, normalized on the fly (one row per wave) ----
  {
    const int r = w;                           // 0..15
    float den = sred0[0][r];
    #pragma unroll
    for (int ww = 1; ww < 16; ++ww) den += sred0[ww][r];
    const float rinv = 1.0f / den;
    float* awb = awout + ((size_t)bh * QL + I0 + r) * TTOT;
    const int sws = (r & 7) << 4;
    #pragma unroll 2
    for (int q = 0; q < 4; ++q) {
      const int X = q * 1024 + lane * 16;               // true column byte
      bf16x8 vv = *(const bf16x8*)((const char*)sbd + r * 4096 + (X ^ sws));
      f32x4 lo, hi;
      #pragma unroll
      for (int k = 0; k < 4; ++k) {
        lo[k] = bf2f((unsigned short)vv[k]) * rinv;
        hi[k] = bf2f((unsigned short)vv[k + 4]) * rinv;
      }
      float* dp = awb + (X >> 1);                       // unswizzled destination
      *(f32x4*)dp = lo;
      *(f32x4*)(dp + 4) = hi;
    }
  }

  // ---- P5b: PV on p (packed V), 4-way split-K across waves; normalize last ----
  {
    const int dc = w & 3, kh = w >> 2;         // kh 0..3
    const unsigned short* vb = vpk + ((size_t)(bh * 4 + dc) * 64) * 512;
    const int sws = (l15 & 7) << 4;
    const int rowbyte = l15 * 4096;
    f32x4 pv = {0.f, 0.f, 0.f, 0.f};
    #pragma unroll 2
    for (int ks = kh * 16; ks < kh * 16 + 16; ++ks) {
      bf16x8 a = *(const bf16x8*)((const char*)sbd +
                  (rowbyte + ((ks * 64 + l4 * 16) ^ sws)));
      bf16x8 vvf = *(const bf16x8*)(vb + ks * 512 + lane * 8);
      pv = mfma16(a, vvf, pv);
    }
    if (kh) {
      #pragma unroll
      for (int j = 0; j < 4; ++j) spv[kh - 1][dc][l4 * 4 + j][l15] = pv[j];
    }
    __syncthreads();
    if (!kh) {
      const size_t obase = ((size_t)b * QL + I0 + l4 * 4) * 1024 + h * 64 + dc * 16 + l15;
      #pragma unroll
      for (int j = 0; j < 4; ++j) {
        const int rl = l4 * 4 + j;
        float den = sred0[0][rl];
        #pragma unroll
        for (int ww = 1; ww < 16; ++ww) den += sred0[ww][rl];
        const float o = (pv[j] + spv[0][dc][rl][l15] + spv[1][dc][rl][l15] +
                         spv[2][dc][rl][l15]) / den;
        cvb[obase + (size_t)j * 1024] = f2bf(o);
      }
    }
  }
}

extern "C" void kernel_launch(void* const* d_in, const int* in_sizes, int n_in,
                              void* d_out, int out_size, void* d_ws, size_t ws_size,
                              hipStream_t stream) {
  (void)in_sizes; (void)n_in; (void)out_size; (void)ws_size;
  const float* key    = (const float*)d_in[0];
  const float* query  = (const float*)d_in[1];
  const float* memory = (const float*)d_in[2];
  const float* pos    = (const float*)d_in[3];
  const int*   mask   = (const int*)d_in[4];
  const float* u      = (const float*)d_in[5];
  const float* v      = (const float*)d_in[6];
  const float* Wk     = (const float*)d_in[7];
  const float* bk     = (const float*)d_in[8];
  const float* Wv     = (const float*)d_in[9];
  const float* bv     = (const float*)d_in[10];
  const float* Wq     = (const float*)d_in[11];
  const float* bq     = (const float*)d_in[12];
  const float* Wp     = (const float*)d_in[13];
  const float* bp     = (const float*)d_in[14];
  const float* Wo     = (const float*)d_in[15];
  const float* bo     = (const float*)d_in[16];

  float* outCV = (float*)d_out;
  float* outAW = outCV + 2097152;

  char* ws = (char*)d_ws;
  const size_t MB = (size_t)1 << 20;
  unsigned short* kpk  = (unsigned short*)(ws + 0);        // packed K     8MB
  unsigned short* vpk  = (unsigned short*)(ws + 8 * MB);   // packed V     8MB
  unsigned short* qupk = (unsigned short*)(ws + 16 * MB);  // packed q+u   4MB
  unsigned short* qvpk = (unsigned short*)(ws + 20 * MB);  // packed q+v   4MB
  unsigned short* ppk  = (unsigned short*)(ws + 24 * MB);  // packed pos   4MB
  unsigned short* cvb  = (unsigned short*)(ws + 28 * MB);  // [b*Q][1024]  4MB
  unsigned short* kcat = (unsigned short*)(ws + 32 * MB);  // [b][t][1024] 8MB
  unsigned short* qry  = (unsigned short*)(ws + 40 * MB);  // 4MB
  unsigned short* posb = (unsigned short*)(ws + 44 * MB);  // 4MB
  unsigned short* wkb  = (unsigned short*)(ws + 48 * MB);  // 2MB (contig with wvb!)
  unsigned short* wvb  = (unsigned short*)(ws + 50 * MB);  // 2MB
  unsigned short* wqb  = (unsigned short*)(ws + 52 * MB);
  unsigned short* wpb  = (unsigned short*)(ws + 54 * MB);
  unsigned short* wob  = (unsigned short*)(ws + 56 * MB);
  unsigned short* mkb  = (unsigned short*)(ws + 58 * MB);  // row-major mask 8MB

  convert_all<<<2048, 256, 0, stream>>>(key, query, memory, pos, mask,
      Wk, Wv, Wq, Wp, Wo, kcat, qry, posb, wkb, wvb, wqb, wpb, wob, mkb);

  // K+V in one launch (B = [Wk;Wv] contiguous), Q+POS in one launch (z)
  gemm_kv<<<dim3(16, 32), 256, 0, stream>>>(kcat, wkb, bk, bv, kpk, vpk);
  gemm_qp<<<dim3(8, 16, 2), 256, 0, stream>>>(qry, posb, wqb, wpb, bq, bp,
      u, v, qupk, qvpk, ppk);

  attn_fused<<<2048, 1024, 0, stream>>>(qupk, qvpk, kpk, ppk, vpk, mkb,
      outAW, cvb);

  gemm_out<<<dim3(8, 16), 256, 0, stream>>>(cvb, wob, bo, outCV);
}

// Round 13
// 241.859 us; speedup vs baseline: 1.3794x; 1.0606x over previous
//
#include <hip/hip_runtime.h>

using bf16x8 = __attribute__((ext_vector_type(8))) short;
using bf16x4 = __attribute__((ext_vector_type(4))) short;
using f32x4  = __attribute__((ext_vector_type(4))) float;

#define NH    16
#define DKH   64
#define TTOT  2048
#define QL    1024

__device__ __forceinline__ float bf2f(unsigned short u) {
  union { unsigned int i; float f; } c; c.i = ((unsigned int)u) << 16; return c.f;
}
__device__ __forceinline__ unsigned short f2bf(float f) {
  union { float f; unsigned int i; } c; c.f = f;
  unsigned int x = c.i;
  x += 0x7fffu + ((x >> 16) & 1u);
  return (unsigned short)(x >> 16);
}
// truncating f32->bf16 (1 op); used where 0.4% rel err is provably harmless
__device__ __forceinline__ unsigned int fbits(float f) {
  union { float f; unsigned int i; } c; c.f = f; return c.i;
}
// HW packed f32->bf16. ORDER-INSENSITIVE uses only (R9 post-mortem):
// applied identically to both GEMM operands, a pairwise K-permutation cancels.
__device__ __forceinline__ unsigned int cvtpk(float lo, float hi) {
  unsigned int r;
  asm("v_cvt_pk_bf16_f32 %0, %1, %2" : "=v"(r) : "v"(lo), "v"(hi));
  return r;
}
// XOR swizzle inside each row (byte bits 4..6 ^= row&7) for 16x2048 bf16 LDS rows
__device__ __forceinline__ int swz(int r, int c) {
  return r * 2048 + ((((c << 1) ^ ((r & 7) << 4))) >> 1);
}
__device__ __forceinline__ f32x4 mfma16(bf16x8 a, bf16x8 b, f32x4 c) {
  return __builtin_amdgcn_mfma_f32_16x16x32_bf16(a, b, c, 0, 0, 0);
}

// ---------------- convert fp32 inputs -> bf16 workspace (vectorized x4) ----------------
__global__ void convert_all(
    const float* __restrict__ key, const float* __restrict__ query,
    const float* __restrict__ memory, const float* __restrict__ pos,
    const int* __restrict__ mask,
    const float* __restrict__ Wk, const float* __restrict__ Wv,
    const float* __restrict__ Wq, const float* __restrict__ Wp,
    const float* __restrict__ Wo,
    unsigned short* __restrict__ kcat, unsigned short* __restrict__ qbf,
    unsigned short* __restrict__ posb,
    unsigned short* __restrict__ wkb, unsigned short* __restrict__ wvb,
    unsigned short* __restrict__ wqb, unsigned short* __restrict__ wpb,
    unsigned short* __restrict__ wob, unsigned short* __restrict__ mkb)
{
  const int g0 = 1048576;            // kcat /4
  const int g1 = g0 + 524288;        // query
  const int g2 = g1 + 524288;        // pos
  const int g3 = g2 + 262144;        // Wk
  const int g4 = g3 + 262144;        // Wv
  const int g5 = g4 + 262144;        // Wq
  const int g6 = g5 + 262144;        // Wp
  const int g7 = g6 + 262144;        // Wo
  const int g8 = g7 + 1048576;       // mask
  for (int g = blockIdx.x * blockDim.x + threadIdx.x; g < g8;
       g += gridDim.x * blockDim.x) {
    const float* src = nullptr;
    unsigned short* dst = nullptr;
    int i;
    if (g < g0) {
      i = g * 4;
      int b = i >> 21, r = i & ((1 << 21) - 1);
      int t = r >> 10, c = r & 1023;
      src = (t < 1024) ? memory + ((size_t)b << 20) + (t << 10) + c
                       : key + ((size_t)b << 20) + ((t - 1024) << 10) + c;
      dst = kcat + i;
    } else if (g < g1) { i = (g - g0) * 4; src = query + i; dst = qbf + i; }
    else if (g < g2)   { i = (g - g1) * 4; src = pos + i;   dst = posb + i; }
    else if (g < g3)   { i = (g - g2) * 4; src = Wk + i;    dst = wkb + i; }
    else if (g < g4)   { i = (g - g3) * 4; src = Wv + i;    dst = wvb + i; }
    else if (g < g5)   { i = (g - g4) * 4; src = Wq + i;    dst = wqb + i; }
    else if (g < g6)   { i = (g - g5) * 4; src = Wp + i;    dst = wpb + i; }
    else if (g < g7)   { i = (g - g6) * 4; src = Wo + i;    dst = wob + i; }
    else {
      i = (g - g7) * 4;
      const int4 mv = *(const int4*)(mask + i);
      const unsigned int nm = f2bf(-1e30f);
      uint2 o;
      o.x = (mv.x ? 0u : nm) | ((mv.y ? 0u : nm) << 16);
      o.y = (mv.z ? 0u : nm) | ((mv.w ? 0u : nm) << 16);
      *(uint2*)(mkb + i) = o;
      continue;
    }
    const float4 v = *(const float4*)src;
    uint2 o;
    o.x = cvtpk(v.x, v.y);
    o.y = cvtpk(v.z, v.w);
    *(uint2*)dst = o;
  }
}

// ------------- shared GEMM core: 128x128 bf16 tile, acc in regs -------------
#define GEMM_CORE() \
  f32x4 acc[4][4] = {}; \
  { \
    bf16x8 ra0 = *(const bf16x8*)Ap0; \
    bf16x8 ra1 = *(const bf16x8*)Ap1; \
    bf16x8 rb0 = *(const bf16x8*)Bp0; \
    bf16x8 rb1 = *(const bf16x8*)Bp1; \
    for (int kt = 0; kt < 32; ++kt) { \
      *(bf16x8*)(sA + swA0) = ra0; \
      *(bf16x8*)(sA + swA1) = ra1; \
      *(bf16x8*)(sB + swA0) = rb0; \
      *(bf16x8*)(sB + swA1) = rb1; \
      __syncthreads(); \
      if (kt + 1 < 32) { \
        const int o = (kt + 1) * 32; \
        ra0 = *(const bf16x8*)(Ap0 + o); \
        ra1 = *(const bf16x8*)(Ap1 + o); \
        rb0 = *(const bf16x8*)(Bp0 + o); \
        rb1 = *(const bf16x8*)(Bp1 + o); \
      } \
      bf16x8 af[4], bfr[4]; \
      _Pragma("unroll") \
      for (int mi = 0; mi < 4; ++mi) { \
        int row = wm + mi * 16 + l15; \
        af[mi] = *(const bf16x8*)(sA + row * 32 + ((l4 ^ ((row >> 1) & 3)) * 8)); \
      } \
      _Pragma("unroll") \
      for (int ni = 0; ni < 4; ++ni) { \
        int row = wn + ni * 16 + l15; \
        bfr[ni] = *(const bf16x8*)(sB + row * 32 + ((l4 ^ ((row >> 1) & 3)) * 8)); \
      } \
      _Pragma("unroll") \
      for (int mi = 0; mi < 4; ++mi) \
        _Pragma("unroll") \
        for (int ni = 0; ni < 4; ++ni) \
          acc[mi][ni] = mfma16(af[mi], bfr[ni], acc[mi][ni]); \
      __syncthreads(); \
    } \
  }

#define GEMM_PTRS(Asrc, Bsrc) \
  const unsigned short* Ap0 = Asrc + (size_t)(bm + am0) * 1024 + as0 * 8; \
  const unsigned short* Ap1 = Asrc + (size_t)(bm + am1) * 1024 + as1 * 8; \
  const unsigned short* Bp0 = Bsrc + (size_t)(bn + am0) * 1024 + as0 * 8; \
  const unsigned short* Bp1 = Bsrc + (size_t)(bn + am1) * 1024 + as1 * 8;

#define GEMM_IDX() \
  __shared__ unsigned short sA[128 * 32]; \
  __shared__ unsigned short sB[128 * 32]; \
  const int tid = threadIdx.x; \
  const int lane = tid & 63; \
  const int wid = tid >> 6; \
  const int wm = (wid >> 1) * 64, wn = (wid & 1) * 64; \
  const int l15 = lane & 15, l4 = lane >> 4; \
  const int am0 = tid >> 2, as0 = tid & 3; \
  const int am1 = (tid + 256) >> 2, as1 = (tid + 256) & 3; \
  const int swA0 = am0 * 32 + ((as0 ^ ((am0 >> 1) & 3)) * 8); \
  const int swA1 = am1 * 32 + ((as1 ^ ((am1 >> 1) & 3)) * 8);

// ALL projections (K, V, q+u/q+v, pos) in ONE 768-block launch.
// id<512: kv (A=kcat[4096], B=[Wk;Wv][2048]); id<640: q; else: pos.
__global__ __launch_bounds__(256, 2) void gemm_proj(
    const unsigned short* __restrict__ kcat, const unsigned short* __restrict__ qry,
    const unsigned short* __restrict__ posb,
    const unsigned short* __restrict__ wkv, const unsigned short* __restrict__ wqb,
    const unsigned short* __restrict__ wpb,
    const float* __restrict__ bk, const float* __restrict__ bv,
    const float* __restrict__ bq, const float* __restrict__ bp,
    const float* __restrict__ uvec, const float* __restrict__ vvec,
    unsigned short* __restrict__ kpk, unsigned short* __restrict__ vpk,
    unsigned short* __restrict__ qupk, unsigned short* __restrict__ qvpk,
    unsigned short* __restrict__ ppk)
{
  GEMM_IDX()
  const int id = blockIdx.x;
  int bm, bn, mode;
  const unsigned short *A, *Bw;
  if (id < 512)      { A = kcat; Bw = wkv; bm = (id >> 4) * 128; bn = (id & 15) * 128; mode = 0; }
  else if (id < 640) { const int t = id - 512; A = qry;  Bw = wqb; bm = (t >> 3) * 128; bn = (t & 7) * 128; mode = 1; }
  else               { const int t = id - 640; A = posb; Bw = wpb; bm = (t >> 3) * 128; bn = (t & 7) * 128; mode = 2; }
  GEMM_PTRS(A, Bw)
  GEMM_CORE()
  #pragma unroll
  for (int mi = 0; mi < 4; ++mi) {
    #pragma unroll
    for (int ni = 0; ni < 4; ++ni) {
      const int col = bn + wn + ni * 16 + l15;
      #pragma unroll
      for (int j = 0; j < 4; ++j) {
        const int row = bm + wm + mi * 16 + l4 * 4 + j;
        if (mode == 0) {
          const bool isK = col < 1024;
          const int cc = col & 1023;
          const float cv = acc[mi][ni][j] + (isK ? bk[cc] : bv[cc]);
          const int bI = row >> 11;
          const int t = row & 2047;
          const int bh2 = bI * NH + (cc >> 6);
          if (isK) {
            const size_t o = ((((size_t)bh2 * 128 + (t >> 4)) * 8 +
                              ((cc & 63) >> 3)) * 16 + (t & 15)) * 8 + (cc & 7);
            kpk[o] = f2bf(cv);
          } else {
            const int dk = cc & 63;
            const size_t o = (((((size_t)bh2 * 4 + (dk >> 4)) * 64 + (t >> 5)) * 4 +
                              ((t >> 3) & 3)) * 16 + (dk & 15)) * 8 + (t & 7);
            vpk[o] = f2bf(cv);
          }
        } else if (mode == 1) {
          const float cv = acc[mi][ni][j] + bq[col];
          const int bI = row >> 10;
          const int t = row & 1023;
          const int bh2 = bI * NH + (col >> 6);
          const size_t o = ((((size_t)bh2 * 64 + (t >> 4)) * 8 +
                            ((col & 63) >> 3)) * 16 + (t & 15)) * 8 + (col & 7);
          qupk[o] = f2bf(cv + uvec[col]);
          qvpk[o] = f2bf(cv + vvec[col]);
        } else {
          const float cv = acc[mi][ni][j] + bp[col];
          const int t = row;                  // single 2048-row batch
          const int h2 = col >> 6;
          const size_t o = ((((size_t)h2 * 128 + (t >> 4)) * 8 +
                            ((col & 63) >> 3)) * 16 + (t & 15)) * 8 + (col & 7);
          ppk[o] = f2bf(cv);
        }
      }
    }
  }
}

// final projection: fp32 row-major out
__global__ __launch_bounds__(256, 2) void gemm_out(
    const unsigned short* __restrict__ A, const unsigned short* __restrict__ Bw,
    const float* __restrict__ bias, float* __restrict__ outf)
{
  GEMM_IDX()
  const int bm = blockIdx.y * 128, bn = blockIdx.x * 128;
  GEMM_PTRS(A, Bw)
  GEMM_CORE()
  #pragma unroll
  for (int mi = 0; mi < 4; ++mi) {
    #pragma unroll
    for (int ni = 0; ni < 4; ++ni) {
      const int col = bn + wn + ni * 16 + l15;
      const float bval = bias[col];
      #pragma unroll
      for (int j = 0; j < 4; ++j) {
        const int row = bm + wm + mi * 16 + l4 * 4 + j;
        outf[(size_t)row * 1024 + col] = acc[mi][ni][j] + bval;
      }
    }
  }
}

// ---------------- fused scores + rel_shift + softmax + aw write + PV ----------------
// 16 q-rows/block, 16 waves, 2 blocks/CU -> 32 waves/CU. 64-VGPR budget;
// unroll 2 caps hoisted loads (R11: unroll-8 spilled). BD and p stored with
// bf16 TRUNCATION (error <=0.4% rel; on s it is x0.125-scaled, on p it
// cancels in p/sum(p)) -- saves ~150 VALU ops/thread vs software RNE.
__global__ __launch_bounds__(1024, 8) void attn_fused(
    const unsigned short* __restrict__ qupk, const unsigned short* __restrict__ qvpk,
    const unsigned short* __restrict__ kpk, const unsigned short* __restrict__ ppk,
    const unsigned short* __restrict__ vpk, const unsigned short* __restrict__ mkb,
    float* __restrict__ awout, unsigned short* __restrict__ cvb)
{
  __shared__ unsigned short sbd[16 * 2048];   // 64 KB: BD -> p (bf16)
  __shared__ float sred0[16][16];             // per-wave row sums
  __shared__ float spv[3][4][16][16];         // split-K partials (kh=1..3)
  const int tid = threadIdx.x;
  const int lane = tid & 63;
  const int w = tid >> 6;                      // 0..15
  const int l15 = lane & 15, l4 = lane >> 4;

  const int wg = blockIdx.x;                   // XCD-grouped, bh interleaved
  const int xcd = wg & 7, idx = wg >> 3;
  const int bh = xcd * 4 + (idx & 3);
  const int tI = idx >> 2;                     // 0..63
  const int I0 = tI * 16;
  const int b = bh >> 4, h = bh & 15;

  // ---- P1: BD via MFMA, scatter-written through the rel_shift mapping ----
  {
    const unsigned short* qvt = qvpk + ((size_t)bh * 64 + tI) * 1024;
    bf16x8 a0 = *(const bf16x8*)(qvt + l4 * 128 + l15 * 8);
    bf16x8 a1 = *(const bf16x8*)(qvt + (4 + l4) * 128 + l15 * 8);
    const unsigned short* ppk_h = ppk + (size_t)h * 131072;
    #pragma unroll 2
    for (int nj = 0; nj < 8; ++nj) {
      const int tile = w * 8 + nj;             // 0..127
      const unsigned short* pt = ppk_h + (size_t)tile * 1024;
      bf16x8 b0 = *(const bf16x8*)(pt + l4 * 128 + l15 * 8);
      bf16x8 b1 = *(const bf16x8*)(pt + (4 + l4) * 128 + l15 * 8);
      f32x4 c = {0.f, 0.f, 0.f, 0.f};
      c = mfma16(a0, b0, c);
      c = mfma16(a1, b1, c);
      const int jj = tile * 16 + l15;
      #pragma unroll
      for (int j = 0; j < 4; ++j) {
        const int rl = l4 * 4 + j;
        const int r = I0 + rl;
        int dst, jp;
        if (jj >= 1023 - r) { dst = rl;     jp = jj + r - 1023; }  // tail part
        else                { dst = rl - 1; jp = jj + r + 1025; }  // wrap part
        if (dst >= 0) sbd[swz(dst, jp)] = (unsigned short)(fbits(c[j]) >> 16);
      }
    }
    // extra BD row (I0+16) feeds last output row's wrap region; 4 tiles/wave
    // (rebalanced across all 16 waves: P1 critical path 16 -> 12 iters)
    if (I0 <= 1006) {
      const unsigned short* qvt2 = qvpk + ((size_t)bh * 64 + tI + 1) * 1024;
      bf16x8 a0e = *(const bf16x8*)(qvt2 + l4 * 128 + l15 * 8);
      bf16x8 a1e = *(const bf16x8*)(qvt2 + (4 + l4) * 128 + l15 * 8);
      #pragma unroll 2
      for (int nj = 0; nj < 4; ++nj) {
        const int tile = w * 4 + nj;           // 0..63
        const unsigned short* pt = ppk_h + (size_t)tile * 1024;
        bf16x8 b0 = *(const bf16x8*)(pt + l4 * 128 + l15 * 8);
        bf16x8 b1 = *(const bf16x8*)(pt + (4 + l4) * 128 + l15 * 8);
        f32x4 c = {0.f, 0.f, 0.f, 0.f};
        c = mfma16(a0e, b0, c);
        c = mfma16(a1e, b1, c);
        const int jj = tile * 16 + l15;
        if (l4 == 0 && jj <= 1006 - I0)
          sbd[swz(15, jj + I0 + 1041)] = (unsigned short)(fbits(c[0]) >> 16);
      }
    }
    if (tid < 16) {   // the zero column injected by the pad/reshape trick
      const int jp = I0 + tid + 1025;
      if (jp < 2048) sbd[swz(tid, jp)] = 0;
    }
  }
  __syncthreads();

  // ---- P2: AC (swapped MFMA) + BD + mask + exp -> p in place, row sums ----
  {
    const unsigned short* qut = qupk + ((size_t)bh * 64 + tI) * 1024;
    bf16x8 a0 = *(const bf16x8*)(qut + l4 * 128 + l15 * 8);
    bf16x8 a1 = *(const bf16x8*)(qut + (4 + l4) * 128 + l15 * 8);
    const unsigned short* kpk_b = kpk + (size_t)bh * 131072;
    const unsigned short* mrow = mkb + ((size_t)b * QL + I0 + l15) * TTOT;
    const int rowbyte = l15 * 4096;            // this thread's q-row = l15
    const int sws = (l15 & 7) << 4;
    float sm = 0.f;
    #pragma unroll 2
    for (int nj = 0; nj < 8; ++nj) {
      const int tile = w * 8 + nj;             // 0..127
      const unsigned short* kt = kpk_b + (size_t)tile * 1024;
      bf16x8 b0 = *(const bf16x8*)(kt + l4 * 128 + l15 * 8);
      bf16x8 b1 = *(const bf16x8*)(kt + (4 + l4) * 128 + l15 * 8);
      f32x4 c = {0.f, 0.f, 0.f, 0.f};
      c = mfma16(b0, a0, c);                   // swapped: rows=K pos, cols=q rows
      c = mfma16(b1, a1, c);
      const int jp0 = tile * 16 + l4 * 4;
      char* sp = (char*)sbd + rowbyte + ((jp0 * 2) ^ sws);
      const bf16x4 bd4 = *(const bf16x4*)sp;
      const bf16x4 m4 = *(const bf16x4*)(mrow + jp0);
      float p[4];
      #pragma unroll
      for (int j = 0; j < 4; ++j) {
        const float s = (c[j] + bf2f((unsigned short)bd4[j])) * 0.125f +
                        bf2f((unsigned short)m4[j]);
        p[j] = __expf(s);
        sm += p[j];
      }
      uint2 pw;   // truncating pack: high half of p1 | high half of p0 >> 16
      pw.x = (fbits(p[1]) & 0xffff0000u) | (fbits(p[0]) >> 16);
      pw.y = (fbits(p[3]) & 0xffff0000u) | (fbits(p[2]) >> 16);
      *(uint2*)sp = pw;
    }
    sm += __shfl_xor(sm, 16, 64);
    sm += __shfl_xor(sm, 32, 64);
    if (l4 == 0) sred0[w][l15] = sm;
  }
  __syncthreads();

  // ---- P5a: aw fp32 write, normalized on the fly (one row per wave) ----
  {
    const int r = w;                           // 0..15
    float den = sred0[0][r];
    #pragma unroll
    for (int ww = 1; ww < 16; ++ww) den += sred0[ww][r];
    const float rinv = 1.0f / den;
    float* awb = awout + ((size_t)bh * QL + I0 + r) * TTOT;
    const int sws = (r & 7) << 4;
    #pragma unroll 2
    for (int q = 0; q < 4; ++q) {
      const int X = q * 1024 + lane * 16;               // true column byte
      bf16x8 vv = *(const bf16x8*)((const char*)sbd + r * 4096 + (X ^ sws));
      f32x4 lo, hi;
      #pragma unroll
      for (int k = 0; k < 4; ++k) {
        lo[k] = bf2f((unsigned short)vv[k]) * rinv;
        hi[k] = bf2f((unsigned short)vv[k + 4]) * rinv;
      }
      float* dp = awb + (X >> 1);                       // unswizzled destination
      *(f32x4*)dp = lo;
      *(f32x4*)(dp + 4) = hi;
    }
  }

  // ---- P5b: PV on p (packed V), 4-way split-K across waves; normalize last ----
  {
    const int dc = w & 3, kh = w >> 2;         // kh 0..3
    const unsigned short* vb = vpk + ((size_t)(bh * 4 + dc) * 64) * 512;
    const int sws = (l15 & 7) << 4;
    const int rowbyte = l15 * 4096;
    f32x4 pv = {0.f, 0.f, 0.f, 0.f};
    #pragma unroll 2
    for (int ks = kh * 16; ks < kh * 16 + 16; ++ks) {
      bf16x8 a = *(const bf16x8*)((const char*)sbd +
                  (rowbyte + ((ks * 64 + l4 * 16) ^ sws)));
      bf16x8 vvf = *(const bf16x8*)(vb + ks * 512 + lane * 8);
      pv = mfma16(a, vvf, pv);
    }
    if (kh) {
      #pragma unroll
      for (int j = 0; j < 4; ++j) spv[kh - 1][dc][l4 * 4 + j][l15] = pv[j];
    }
    __syncthreads();
    if (!kh) {
      const size_t obase = ((size_t)b * QL + I0 + l4 * 4) * 1024 + h * 64 + dc * 16 + l15;
      #pragma unroll
      for (int j = 0; j < 4; ++j) {
        const int rl = l4 * 4 + j;
        float den = sred0[0][rl];
        #pragma unroll
        for (int ww = 1; ww < 16; ++ww) den += sred0[ww][rl];
        const float o = (pv[j] + spv[0][dc][rl][l15] + spv[1][dc][rl][l15] +
                         spv[2][dc][rl][l15]) / den;
        cvb[obase + (size_t)j * 1024] = f2bf(o);
      }
    }
  }
}

extern "C" void kernel_launch(void* const* d_in, const int* in_sizes, int n_in,
                              void* d_out, int out_size, void* d_ws, size_t ws_size,
                              hipStream_t stream) {
  (void)in_sizes; (void)n_in; (void)out_size; (void)ws_size;
  const float* key    = (const float*)d_in[0];
  const float* query  = (const float*)d_in[1];
  const float* memory = (const float*)d_in[2];
  const float* pos    = (const float*)d_in[3];
  const int*   mask   = (const int*)d_in[4];
  const float* u      = (const float*)d_in[5];
  const float* v      = (const float*)d_in[6];
  const float* Wk     = (const float*)d_in[7];
  const float* bk     = (const float*)d_in[8];
  const float* Wv     = (const float*)d_in[9];
  const float* bv     = (const float*)d_in[10];
  const float* Wq     = (const float*)d_in[11];
  const float* bq     = (const float*)d_in[12];
  const float* Wp     = (const float*)d_in[13];
  const float* bp     = (const float*)d_in[14];
  const float* Wo     = (const float*)d_in[15];
  const float* bo     = (const float*)d_in[16];

  float* outCV = (float*)d_out;
  float* outAW = outCV + 2097152;

  char* ws = (char*)d_ws;
  const size_t MB = (size_t)1 << 20;
  unsigned short* kpk  = (unsigned short*)(ws + 0);        // packed K     8MB
  unsigned short* vpk  = (unsigned short*)(ws + 8 * MB);   // packed V     8MB
  unsigned short* qupk = (unsigned short*)(ws + 16 * MB);  // packed q+u   4MB
  unsigned short* qvpk = (unsigned short*)(ws + 20 * MB);  // packed q+v   4MB
  unsigned short* ppk  = (unsigned short*)(ws + 24 * MB);  // packed pos   4MB
  unsigned short* cvb  = (unsigned short*)(ws + 28 * MB);  // [b*Q][1024]  4MB
  unsigned short* kcat = (unsigned short*)(ws + 32 * MB);  // [b][t][1024] 8MB
  unsigned short* qry  = (unsigned short*)(ws + 40 * MB);  // 4MB
  unsigned short* posb = (unsigned short*)(ws + 44 * MB);  // 4MB
  unsigned short* wkb  = (unsigned short*)(ws + 48 * MB);  // 2MB (contig with wvb!)
  unsigned short* wvb  = (unsigned short*)(ws + 50 * MB);  // 2MB
  unsigned short* wqb  = (unsigned short*)(ws + 52 * MB);
  unsigned short* wpb  = (unsigned short*)(ws + 54 * MB);
  unsigned short* wob  = (unsigned short*)(ws + 56 * MB);
  unsigned short* mkb  = (unsigned short*)(ws + 58 * MB);  // row-major mask 8MB

  convert_all<<<2048, 256, 0, stream>>>(key, query, memory, pos, mask,
      Wk, Wv, Wq, Wp, Wo, kcat, qry, posb, wkb, wvb, wqb, wpb, wob, mkb);

  // ALL projections in one 768-block launch (kv 512 + q 128 + pos 128)
  gemm_proj<<<768, 256, 0, stream>>>(kcat, qry, posb, wkb, wqb, wpb,
      bk, bv, bq, bp, u, v, kpk, vpk, qupk, qvpk, ppk);

  attn_fused<<<2048, 1024, 0, stream>>>(qupk, qvpk, kpk, ppk, vpk, mkb,
      outAW, cvb);

  gemm_out<<<dim3(8, 16), 256, 0, stream>>>(cvb, wob, bo, outCV);
}

// Round 14
// 237.086 us; speedup vs baseline: 1.4071x; 1.0201x over previous
//
#include <hip/hip_runtime.h>

using bf16x8 = __attribute__((ext_vector_type(8))) short;
using bf16x4 = __attribute__((ext_vector_type(4))) short;
using f32x4  = __attribute__((ext_vector_type(4))) float;

#define NH    16
#define DKH   64
#define TTOT  2048
#define QL    1024

__device__ __forceinline__ float bf2f(unsigned short u) {
  union { unsigned int i; float f; } c; c.i = ((unsigned int)u) << 16; return c.f;
}
__device__ __forceinline__ unsigned short f2bf(float f) {
  union { float f; unsigned int i; } c; c.f = f;
  unsigned int x = c.i;
  x += 0x7fffu + ((x >> 16) & 1u);
  return (unsigned short)(x >> 16);
}
// truncating f32->bf16 (1 op); used where 0.4% rel err is provably harmless
__device__ __forceinline__ unsigned int fbits(float f) {
  union { float f; unsigned int i; } c; c.f = f; return c.i;
}
// HW packed f32->bf16. ORDER-INSENSITIVE uses only (R9 post-mortem):
// applied identically to both GEMM operands, a pairwise K-permutation cancels.
__device__ __forceinline__ unsigned int cvtpk(float lo, float hi) {
  unsigned int r;
  asm("v_cvt_pk_bf16_f32 %0, %1, %2" : "=v"(r) : "v"(lo), "v"(hi));
  return r;
}
// native base-2 exp (v_exp_f32 computes 2^x); pure-VALU asm, dep-tracked
__device__ __forceinline__ float exp2_hw(float x) {
  float r;
  asm("v_exp_f32 %0, %1" : "=v"(r) : "v"(x));
  return r;
}
// XOR swizzle inside each row (byte bits 4..6 ^= row&7) for 16x2048 bf16 LDS rows
__device__ __forceinline__ int swz(int r, int c) {
  return r * 2048 + ((((c << 1) ^ ((r & 7) << 4))) >> 1);
}
__device__ __forceinline__ f32x4 mfma16(bf16x8 a, bf16x8 b, f32x4 c) {
  return __builtin_amdgcn_mfma_f32_16x16x32_bf16(a, b, c, 0, 0, 0);
}

// ---------------- convert fp32 inputs -> bf16 workspace (vectorized x4) ----------------
// Mask bias stored PRE-SCALED by log2(e) so P2 can use 2^x directly.
__global__ void convert_all(
    const float* __restrict__ key, const float* __restrict__ query,
    const float* __restrict__ memory, const float* __restrict__ pos,
    const int* __restrict__ mask,
    const float* __restrict__ Wk, const float* __restrict__ Wv,
    const float* __restrict__ Wq, const float* __restrict__ Wp,
    const float* __restrict__ Wo,
    unsigned short* __restrict__ kcat, unsigned short* __restrict__ qbf,
    unsigned short* __restrict__ posb,
    unsigned short* __restrict__ wkb, unsigned short* __restrict__ wvb,
    unsigned short* __restrict__ wqb, unsigned short* __restrict__ wpb,
    unsigned short* __restrict__ wob, unsigned short* __restrict__ mkb)
{
  const int g0 = 1048576;            // kcat /4
  const int g1 = g0 + 524288;        // query
  const int g2 = g1 + 524288;        // pos
  const int g3 = g2 + 262144;        // Wk
  const int g4 = g3 + 262144;        // Wv
  const int g5 = g4 + 262144;        // Wq
  const int g6 = g5 + 262144;        // Wp
  const int g7 = g6 + 262144;        // Wo
  const int g8 = g7 + 1048576;       // mask
  for (int g = blockIdx.x * blockDim.x + threadIdx.x; g < g8;
       g += gridDim.x * blockDim.x) {
    const float* src = nullptr;
    unsigned short* dst = nullptr;
    int i;
    if (g < g0) {
      i = g * 4;
      int b = i >> 21, r = i & ((1 << 21) - 1);
      int t = r >> 10, c = r & 1023;
      src = (t < 1024) ? memory + ((size_t)b << 20) + (t << 10) + c
                       : key + ((size_t)b << 20) + ((t - 1024) << 10) + c;
      dst = kcat + i;
    } else if (g < g1) { i = (g - g0) * 4; src = query + i; dst = qbf + i; }
    else if (g < g2)   { i = (g - g1) * 4; src = pos + i;   dst = posb + i; }
    else if (g < g3)   { i = (g - g2) * 4; src = Wk + i;    dst = wkb + i; }
    else if (g < g4)   { i = (g - g3) * 4; src = Wv + i;    dst = wvb + i; }
    else if (g < g5)   { i = (g - g4) * 4; src = Wq + i;    dst = wqb + i; }
    else if (g < g6)   { i = (g - g5) * 4; src = Wp + i;    dst = wpb + i; }
    else if (g < g7)   { i = (g - g6) * 4; src = Wo + i;    dst = wob + i; }
    else {
      i = (g - g7) * 4;
      const int4 mv = *(const int4*)(mask + i);
      const unsigned int nm = f2bf(-1.4426950e30f);   // -1e30 * log2(e)
      uint2 o;
      o.x = (mv.x ? 0u : nm) | ((mv.y ? 0u : nm) << 16);
      o.y = (mv.z ? 0u : nm) | ((mv.w ? 0u : nm) << 16);
      *(uint2*)(mkb + i) = o;
      continue;
    }
    const float4 v = *(const float4*)src;
    uint2 o;
    o.x = cvtpk(v.x, v.y);
    o.y = cvtpk(v.z, v.w);
    *(uint2*)dst = o;
  }
}

// ------------- shared GEMM core: 128x128 bf16 tile, acc in regs -------------
#define GEMM_CORE() \
  f32x4 acc[4][4] = {}; \
  { \
    bf16x8 ra0 = *(const bf16x8*)Ap0; \
    bf16x8 ra1 = *(const bf16x8*)Ap1; \
    bf16x8 rb0 = *(const bf16x8*)Bp0; \
    bf16x8 rb1 = *(const bf16x8*)Bp1; \
    for (int kt = 0; kt < 32; ++kt) { \
      *(bf16x8*)(sA + swA0) = ra0; \
      *(bf16x8*)(sA + swA1) = ra1; \
      *(bf16x8*)(sB + swA0) = rb0; \
      *(bf16x8*)(sB + swA1) = rb1; \
      __syncthreads(); \
      if (kt + 1 < 32) { \
        const int o = (kt + 1) * 32; \
        ra0 = *(const bf16x8*)(Ap0 + o); \
        ra1 = *(const bf16x8*)(Ap1 + o); \
        rb0 = *(const bf16x8*)(Bp0 + o); \
        rb1 = *(const bf16x8*)(Bp1 + o); \
      } \
      bf16x8 af[4], bfr[4]; \
      _Pragma("unroll") \
      for (int mi = 0; mi < 4; ++mi) { \
        int row = wm + mi * 16 + l15; \
        af[mi] = *(const bf16x8*)(sA + row * 32 + ((l4 ^ ((row >> 1) & 3)) * 8)); \
      } \
      _Pragma("unroll") \
      for (int ni = 0; ni < 4; ++ni) { \
        int row = wn + ni * 16 + l15; \
        bfr[ni] = *(const bf16x8*)(sB + row * 32 + ((l4 ^ ((row >> 1) & 3)) * 8)); \
      } \
      _Pragma("unroll") \
      for (int mi = 0; mi < 4; ++mi) \
        _Pragma("unroll") \
        for (int ni = 0; ni < 4; ++ni) \
          acc[mi][ni] = mfma16(af[mi], bfr[ni], acc[mi][ni]); \
      __syncthreads(); \
    } \
  }

#define GEMM_PTRS(Asrc, Bsrc) \
  const unsigned short* Ap0 = Asrc + (size_t)(bm + am0) * 1024 + as0 * 8; \
  const unsigned short* Ap1 = Asrc + (size_t)(bm + am1) * 1024 + as1 * 8; \
  const unsigned short* Bp0 = Bsrc + (size_t)(bn + am0) * 1024 + as0 * 8; \
  const unsigned short* Bp1 = Bsrc + (size_t)(bn + am1) * 1024 + as1 * 8;

#define GEMM_IDX() \
  __shared__ unsigned short sA[128 * 32]; \
  __shared__ unsigned short sB[128 * 32]; \
  const int tid = threadIdx.x; \
  const int lane = tid & 63; \
  const int wid = tid >> 6; \
  const int wm = (wid >> 1) * 64, wn = (wid & 1) * 64; \
  const int l15 = lane & 15, l4 = lane >> 4; \
  const int am0 = tid >> 2, as0 = tid & 3; \
  const int am1 = (tid + 256) >> 2, as1 = (tid + 256) & 3; \
  const int swA0 = am0 * 32 + ((as0 ^ ((am0 >> 1) & 3)) * 8); \
  const int swA1 = am1 * 32 + ((as1 ^ ((am1 >> 1) & 3)) * 8);

// ALL projections (K, V, q+u/q+v, pos) in ONE 768-block launch.
// id<512: kv (A=kcat[4096], B=[Wk;Wv][2048]); id<640: q; else: pos.
__global__ __launch_bounds__(256, 2) void gemm_proj(
    const unsigned short* __restrict__ kcat, const unsigned short* __restrict__ qry,
    const unsigned short* __restrict__ posb,
    const unsigned short* __restrict__ wkv, const unsigned short* __restrict__ wqb,
    const unsigned short* __restrict__ wpb,
    const float* __restrict__ bk, const float* __restrict__ bv,
    const float* __restrict__ bq, const float* __restrict__ bp,
    const float* __restrict__ uvec, const float* __restrict__ vvec,
    unsigned short* __restrict__ kpk, unsigned short* __restrict__ vpk,
    unsigned short* __restrict__ qupk, unsigned short* __restrict__ qvpk,
    unsigned short* __restrict__ ppk)
{
  GEMM_IDX()
  const int id = blockIdx.x;
  int bm, bn, mode;
  const unsigned short *A, *Bw;
  if (id < 512)      { A = kcat; Bw = wkv; bm = (id >> 4) * 128; bn = (id & 15) * 128; mode = 0; }
  else if (id < 640) { const int t = id - 512; A = qry;  Bw = wqb; bm = (t >> 3) * 128; bn = (t & 7) * 128; mode = 1; }
  else               { const int t = id - 640; A = posb; Bw = wpb; bm = (t >> 3) * 128; bn = (t & 7) * 128; mode = 2; }
  GEMM_PTRS(A, Bw)
  GEMM_CORE()
  #pragma unroll
  for (int mi = 0; mi < 4; ++mi) {
    #pragma unroll
    for (int ni = 0; ni < 4; ++ni) {
      const int col = bn + wn + ni * 16 + l15;
      #pragma unroll
      for (int j = 0; j < 4; ++j) {
        const int row = bm + wm + mi * 16 + l4 * 4 + j;
        if (mode == 0) {
          const bool isK = col < 1024;
          const int cc = col & 1023;
          const float cv = acc[mi][ni][j] + (isK ? bk[cc] : bv[cc]);
          const int bI = row >> 11;
          const int t = row & 2047;
          const int bh2 = bI * NH + (cc >> 6);
          if (isK) {
            const size_t o = ((((size_t)bh2 * 128 + (t >> 4)) * 8 +
                              ((cc & 63) >> 3)) * 16 + (t & 15)) * 8 + (cc & 7);
            kpk[o] = f2bf(cv);
          } else {
            const int dk = cc & 63;
            const size_t o = (((((size_t)bh2 * 4 + (dk >> 4)) * 64 + (t >> 5)) * 4 +
                              ((t >> 3) & 3)) * 16 + (dk & 15)) * 8 + (t & 7);
            vpk[o] = f2bf(cv);
          }
        } else if (mode == 1) {
          const float cv = acc[mi][ni][j] + bq[col];
          const int bI = row >> 10;
          const int t = row & 1023;
          const int bh2 = bI * NH + (col >> 6);
          const size_t o = ((((size_t)bh2 * 64 + (t >> 4)) * 8 +
                            ((col & 63) >> 3)) * 16 + (t & 15)) * 8 + (col & 7);
          qupk[o] = f2bf(cv + uvec[col]);
          qvpk[o] = f2bf(cv + vvec[col]);
        } else {
          const float cv = acc[mi][ni][j] + bp[col];
          const int t = row;                  // single 2048-row batch
          const int h2 = col >> 6;
          const size_t o = ((((size_t)h2 * 128 + (t >> 4)) * 8 +
                            ((col & 63) >> 3)) * 16 + (t & 15)) * 8 + (col & 7);
          ppk[o] = f2bf(cv);
        }
      }
    }
  }
}

// final projection: fp32 row-major out
__global__ __launch_bounds__(256, 2) void gemm_out(
    const unsigned short* __restrict__ A, const unsigned short* __restrict__ Bw,
    const float* __restrict__ bias, float* __restrict__ outf)
{
  GEMM_IDX()
  const int bm = blockIdx.y * 128, bn = blockIdx.x * 128;
  GEMM_PTRS(A, Bw)
  GEMM_CORE()
  #pragma unroll
  for (int mi = 0; mi < 4; ++mi) {
    #pragma unroll
    for (int ni = 0; ni < 4; ++ni) {
      const int col = bn + wn + ni * 16 + l15;
      const float bval = bias[col];
      #pragma unroll
      for (int j = 0; j < 4; ++j) {
        const int row = bm + wm + mi * 16 + l4 * 4 + j;
        outf[(size_t)row * 1024 + col] = acc[mi][ni][j] + bval;
      }
    }
  }
}

// ---------------- fused scores + rel_shift + softmax + aw write + PV ----------------
// 16 q-rows/block, 16 waves, 2 blocks/CU -> 32 waves/CU. 64-VGPR budget;
// P1/P2 unroll 2 caps hoisted loads (R11: unroll-8 spilled); P5a/P5b deeper
// (small per-iter footprint). p = 2^(fma(c+bd, 0.125*log2e, m2)) with the
// mask pre-scaled by log2e -- one fewer VALU and shorter chain per element.
__global__ __launch_bounds__(1024, 8) void attn_fused(
    const unsigned short* __restrict__ qupk, const unsigned short* __restrict__ qvpk,
    const unsigned short* __restrict__ kpk, const unsigned short* __restrict__ ppk,
    const unsigned short* __restrict__ vpk, const unsigned short* __restrict__ mkb,
    float* __restrict__ awout, unsigned short* __restrict__ cvb)
{
  __shared__ unsigned short sbd[16 * 2048];   // 64 KB: BD -> p (bf16)
  __shared__ float sred0[16][16];             // per-wave row sums
  __shared__ float spv[3][4][16][16];         // split-K partials (kh=1..3)
  const int tid = threadIdx.x;
  const int lane = tid & 63;
  const int w = tid >> 6;                      // 0..15
  const int l15 = lane & 15, l4 = lane >> 4;

  const int wg = blockIdx.x;                   // XCD-grouped, bh interleaved
  const int xcd = wg & 7, idx = wg >> 3;
  const int bh = xcd * 4 + (idx & 3);
  const int tI = idx >> 2;                     // 0..63
  const int I0 = tI * 16;
  const int b = bh >> 4, h = bh & 15;

  // ---- P1: BD via MFMA, scatter-written through the rel_shift mapping ----
  {
    const unsigned short* qvt = qvpk + ((size_t)bh * 64 + tI) * 1024;
    bf16x8 a0 = *(const bf16x8*)(qvt + l4 * 128 + l15 * 8);
    bf16x8 a1 = *(const bf16x8*)(qvt + (4 + l4) * 128 + l15 * 8);
    const unsigned short* ppk_h = ppk + (size_t)h * 131072;
    #pragma unroll 2
    for (int nj = 0; nj < 8; ++nj) {
      const int tile = w * 8 + nj;             // 0..127
      const unsigned short* pt = ppk_h + (size_t)tile * 1024;
      bf16x8 b0 = *(const bf16x8*)(pt + l4 * 128 + l15 * 8);
      bf16x8 b1 = *(const bf16x8*)(pt + (4 + l4) * 128 + l15 * 8);
      f32x4 c = {0.f, 0.f, 0.f, 0.f};
      c = mfma16(a0, b0, c);
      c = mfma16(a1, b1, c);
      const int jj = tile * 16 + l15;
      #pragma unroll
      for (int j = 0; j < 4; ++j) {
        const int rl = l4 * 4 + j;
        const int r = I0 + rl;
        int dst, jp;
        if (jj >= 1023 - r) { dst = rl;     jp = jj + r - 1023; }  // tail part
        else                { dst = rl - 1; jp = jj + r + 1025; }  // wrap part
        if (dst >= 0) sbd[swz(dst, jp)] = (unsigned short)(fbits(c[j]) >> 16);
      }
    }
    // extra BD row (I0+16) feeds last output row's wrap region; 4 tiles/wave
    if (I0 <= 1006) {
      const unsigned short* qvt2 = qvpk + ((size_t)bh * 64 + tI + 1) * 1024;
      bf16x8 a0e = *(const bf16x8*)(qvt2 + l4 * 128 + l15 * 8);
      bf16x8 a1e = *(const bf16x8*)(qvt2 + (4 + l4) * 128 + l15 * 8);
      #pragma unroll 2
      for (int nj = 0; nj < 4; ++nj) {
        const int tile = w * 4 + nj;           // 0..63
        const unsigned short* pt = ppk_h + (size_t)tile * 1024;
        bf16x8 b0 = *(const bf16x8*)(pt + l4 * 128 + l15 * 8);
        bf16x8 b1 = *(const bf16x8*)(pt + (4 + l4) * 128 + l15 * 8);
        f32x4 c = {0.f, 0.f, 0.f, 0.f};
        c = mfma16(a0e, b0, c);
        c = mfma16(a1e, b1, c);
        const int jj = tile * 16 + l15;
        if (l4 == 0 && jj <= 1006 - I0)
          sbd[swz(15, jj + I0 + 1041)] = (unsigned short)(fbits(c[0]) >> 16);
      }
    }
    if (tid < 16) {   // the zero column injected by the pad/reshape trick
      const int jp = I0 + tid + 1025;
      if (jp < 2048) sbd[swz(tid, jp)] = 0;
    }
  }
  __syncthreads();

  // ---- P2: AC (swapped MFMA) + BD + mask + 2^x -> p in place, row sums ----
  {
    const unsigned short* qut = qupk + ((size_t)bh * 64 + tI) * 1024;
    bf16x8 a0 = *(const bf16x8*)(qut + l4 * 128 + l15 * 8);
    bf16x8 a1 = *(const bf16x8*)(qut + (4 + l4) * 128 + l15 * 8);
    const unsigned short* kpk_b = kpk + (size_t)bh * 131072;
    const unsigned short* mrow = mkb + ((size_t)b * QL + I0 + l15) * TTOT;
    const int rowbyte = l15 * 4096;            // this thread's q-row = l15
    const int sws = (l15 & 7) << 4;
    float sm = 0.f;
    #pragma unroll 2
    for (int nj = 0; nj < 8; ++nj) {
      const int tile = w * 8 + nj;             // 0..127
      const unsigned short* kt = kpk_b + (size_t)tile * 1024;
      bf16x8 b0 = *(const bf16x8*)(kt + l4 * 128 + l15 * 8);
      bf16x8 b1 = *(const bf16x8*)(kt + (4 + l4) * 128 + l15 * 8);
      f32x4 c = {0.f, 0.f, 0.f, 0.f};
      c = mfma16(b0, a0, c);                   // swapped: rows=K pos, cols=q rows
      c = mfma16(b1, a1, c);
      const int jp0 = tile * 16 + l4 * 4;
      char* sp = (char*)sbd + rowbyte + ((jp0 * 2) ^ sws);
      const bf16x4 bd4 = *(const bf16x4*)sp;
      const bf16x4 m4 = *(const bf16x4*)(mrow + jp0);
      float p[4];
      #pragma unroll
      for (int j = 0; j < 4; ++j) {
        // s*log2e = (c+bd) * (0.125*log2e) + m2   (m2 pre-scaled by log2e)
        const float s2 = fmaf(c[j] + bf2f((unsigned short)bd4[j]), 0.18033688f,
                              bf2f((unsigned short)m4[j]));
        p[j] = exp2_hw(s2);
        sm += p[j];
      }
      uint2 pw;   // truncating pack
      pw.x = (fbits(p[1]) & 0xffff0000u) | (fbits(p[0]) >> 16);
      pw.y = (fbits(p[3]) & 0xffff0000u) | (fbits(p[2]) >> 16);
      *(uint2*)sp = pw;
    }
    sm += __shfl_xor(sm, 16, 64);
    sm += __shfl_xor(sm, 32, 64);
    if (l4 == 0) sred0[w][l15] = sm;
  }
  __syncthreads();

  // ---- P5a: aw fp32 write, normalized on the fly (one row per wave) ----
  {
    const int r = w;                           // 0..15
    float den = sred0[0][r];
    #pragma unroll
    for (int ww = 1; ww < 16; ++ww) den += sred0[ww][r];
    const float rinv = 1.0f / den;
    float* awb = awout + ((size_t)bh * QL + I0 + r) * TTOT;
    const int sws = (r & 7) << 4;
    #pragma unroll
    for (int q = 0; q < 4; ++q) {
      const int X = q * 1024 + lane * 16;               // true column byte
      bf16x8 vv = *(const bf16x8*)((const char*)sbd + r * 4096 + (X ^ sws));
      f32x4 lo, hi;
      #pragma unroll
      for (int k = 0; k < 4; ++k) {
        lo[k] = bf2f((unsigned short)vv[k]) * rinv;
        hi[k] = bf2f((unsigned short)vv[k + 4]) * rinv;
      }
      float* dp = awb + (X >> 1);                       // unswizzled destination
      *(f32x4*)dp = lo;
      *(f32x4*)(dp + 4) = hi;
    }
  }

  // ---- P5b: PV on p (packed V), 4-way split-K across waves; normalize last ----
  {
    const int dc = w & 3, kh = w >> 2;         // kh 0..3
    const unsigned short* vb = vpk + ((size_t)(bh * 4 + dc) * 64) * 512;
    const int sws = (l15 & 7) << 4;
    const int rowbyte = l15 * 4096;
    f32x4 pv = {0.f, 0.f, 0.f, 0.f};
    #pragma unroll 4
    for (int ks = kh * 16; ks < kh * 16 + 16; ++ks) {
      bf16x8 a = *(const bf16x8*)((const char*)sbd +
                  (rowbyte + ((ks * 64 + l4 * 16) ^ sws)));
      bf16x8 vvf = *(const bf16x8*)(vb + ks * 512 + lane * 8);
      pv = mfma16(a, vvf, pv);
    }
    if (kh) {
      #pragma unroll
      for (int j = 0; j < 4; ++j) spv[kh - 1][dc][l4 * 4 + j][l15] = pv[j];
    }
    __syncthreads();
    if (!kh) {
      const size_t obase = ((size_t)b * QL + I0 + l4 * 4) * 1024 + h * 64 + dc * 16 + l15;
      #pragma unroll
      for (int j = 0; j < 4; ++j) {
        const int rl = l4 * 4 + j;
        float den = sred0[0][rl];
        #pragma unroll
        for (int ww = 1; ww < 16; ++ww) den += sred0[ww][rl];
        const float o = (pv[j] + spv[0][dc][rl][l15] + spv[1][dc][rl][l15] +
                         spv[2][dc][rl][l15]) / den;
        cvb[obase + (size_t)j * 1024] = f2bf(o);
      }
    }
  }
}

extern "C" void kernel_launch(void* const* d_in, const int* in_sizes, int n_in,
                              void* d_out, int out_size, void* d_ws, size_t ws_size,
                              hipStream_t stream) {
  (void)in_sizes; (void)n_in; (void)out_size; (void)ws_size;
  const float* key    = (const float*)d_in[0];
  const float* query  = (const float*)d_in[1];
  const float* memory = (const float*)d_in[2];
  const float* pos    = (const float*)d_in[3];
  const int*   mask   = (const int*)d_in[4];
  const float* u      = (const float*)d_in[5];
  const float* v      = (const float*)d_in[6];
  const float* Wk     = (const float*)d_in[7];
  const float* bk     = (const float*)d_in[8];
  const float* Wv     = (const float*)d_in[9];
  const float* bv     = (const float*)d_in[10];
  const float* Wq     = (const float*)d_in[11];
  const float* bq     = (const float*)d_in[12];
  const float* Wp     = (const float*)d_in[13];
  const float* bp     = (const float*)d_in[14];
  const float* Wo     = (const float*)d_in[15];
  const float* bo     = (const float*)d_in[16];

  float* outCV = (float*)d_out;
  float* outAW = outCV + 2097152;

  char* ws = (char*)d_ws;
  const size_t MB = (size_t)1 << 20;
  unsigned short* kpk  = (unsigned short*)(ws + 0);        // packed K     8MB
  unsigned short* vpk  = (unsigned short*)(ws + 8 * MB);   // packed V     8MB
  unsigned short* qupk = (unsigned short*)(ws + 16 * MB);  // packed q+u   4MB
  unsigned short* qvpk = (unsigned short*)(ws + 20 * MB);  // packed q+v   4MB
  unsigned short* ppk  = (unsigned short*)(ws + 24 * MB);  // packed pos   4MB
  unsigned short* cvb  = (unsigned short*)(ws + 28 * MB);  // [b*Q][1024]  4MB
  unsigned short* kcat = (unsigned short*)(ws + 32 * MB);  // [b][t][1024] 8MB
  unsigned short* qry  = (unsigned short*)(ws + 40 * MB);  // 4MB
  unsigned short* posb = (unsigned short*)(ws + 44 * MB);  // 4MB
  unsigned short* wkb  = (unsigned short*)(ws + 48 * MB);  // 2MB (contig with wvb!)
  unsigned short* wvb  = (unsigned short*)(ws + 50 * MB);  // 2MB
  unsigned short* wqb  = (unsigned short*)(ws + 52 * MB);
  unsigned short* wpb  = (unsigned short*)(ws + 54 * MB);
  unsigned short* wob  = (unsigned short*)(ws + 56 * MB);
  unsigned short* mkb  = (unsigned short*)(ws + 58 * MB);  // row-major mask 8MB

  convert_all<<<2048, 256, 0, stream>>>(key, query, memory, pos, mask,
      Wk, Wv, Wq, Wp, Wo, kcat, qry, posb, wkb, wvb, wqb, wpb, wob, mkb);

  // ALL projections in one 768-block launch (kv 512 + q 128 + pos 128)
  gemm_proj<<<768, 256, 0, stream>>>(kcat, qry, posb, wkb, wqb, wpb,
      bk, bv, bq, bp, u, v, kpk, vpk, qupk, qvpk, ppk);

  attn_fused<<<2048, 1024, 0, stream>>>(qupk, qvpk, kpk, ppk, vpk, mkb,
      outAW, cvb);

  gemm_out<<<dim3(8, 16), 256, 0, stream>>>(cvb, wob, bo, outCV);
}

// Round 15
// 232.306 us; speedup vs baseline: 1.4361x; 1.0206x over previous
//
#include <hip/hip_runtime.h>

using bf16x8 = __attribute__((ext_vector_type(8))) short;
using bf16x4 = __attribute__((ext_vector_type(4))) short;
using f32x4  = __attribute__((ext_vector_type(4))) float;

#define NH    16
#define DKH   64
#define TTOT  2048
#define QL    1024

__device__ __forceinline__ float bf2f(unsigned short u) {
  union { unsigned int i; float f; } c; c.i = ((unsigned int)u) << 16; return c.f;
}
__device__ __forceinline__ unsigned short f2bf(float f) {
  union { float f; unsigned int i; } c; c.f = f;
  unsigned int x = c.i;
  x += 0x7fffu + ((x >> 16) & 1u);
  return (unsigned short)(x >> 16);
}
// truncating f32->bf16 (1 op); used where 0.4% rel err is provably harmless
__device__ __forceinline__ unsigned int fbits(float f) {
  union { float f; unsigned int i; } c; c.f = f; return c.i;
}
// HW packed f32->bf16. ORDER-INSENSITIVE uses only (R9 post-mortem):
// applied identically to both GEMM operands, a pairwise K-permutation cancels.
__device__ __forceinline__ unsigned int cvtpk(float lo, float hi) {
  unsigned int r;
  asm("v_cvt_pk_bf16_f32 %0, %1, %2" : "=v"(r) : "v"(lo), "v"(hi));
  return r;
}
// native base-2 exp (v_exp_f32 computes 2^x); pure-VALU asm, dep-tracked
__device__ __forceinline__ float exp2_hw(float x) {
  float r;
  asm("v_exp_f32 %0, %1" : "=v"(r) : "v"(x));
  return r;
}
// XOR swizzle inside each row (byte bits 4..6 ^= row&7) for 16x2048 bf16 LDS rows
__device__ __forceinline__ int swz(int r, int c) {
  return r * 2048 + ((((c << 1) ^ ((r & 7) << 4))) >> 1);
}
__device__ __forceinline__ f32x4 mfma16(bf16x8 a, bf16x8 b, f32x4 c) {
  return __builtin_amdgcn_mfma_f32_16x16x32_bf16(a, b, c, 0, 0, 0);
}

// ---------------- convert fp32 inputs -> bf16 workspace (vectorized x4) ----------------
// Mask bias stored PRE-SCALED by log2(e) so P2 can use 2^x directly.
__global__ void convert_all(
    const float* __restrict__ key, const float* __restrict__ query,
    const float* __restrict__ memory, const float* __restrict__ pos,
    const int* __restrict__ mask,
    const float* __restrict__ Wk, const float* __restrict__ Wv,
    const float* __restrict__ Wq, const float* __restrict__ Wp,
    const float* __restrict__ Wo,
    unsigned short* __restrict__ kcat, unsigned short* __restrict__ qbf,
    unsigned short* __restrict__ posb,
    unsigned short* __restrict__ wkb, unsigned short* __restrict__ wvb,
    unsigned short* __restrict__ wqb, unsigned short* __restrict__ wpb,
    unsigned short* __restrict__ wob, unsigned short* __restrict__ mkb)
{
  const int g0 = 1048576;            // kcat /4
  const int g1 = g0 + 524288;        // query
  const int g2 = g1 + 524288;        // pos
  const int g3 = g2 + 262144;        // Wk
  const int g4 = g3 + 262144;        // Wv
  const int g5 = g4 + 262144;        // Wq
  const int g6 = g5 + 262144;        // Wp
  const int g7 = g6 + 262144;        // Wo
  const int g8 = g7 + 1048576;       // mask
  for (int g = blockIdx.x * blockDim.x + threadIdx.x; g < g8;
       g += gridDim.x * blockDim.x) {
    const float* src = nullptr;
    unsigned short* dst = nullptr;
    int i;
    if (g < g0) {
      i = g * 4;
      int b = i >> 21, r = i & ((1 << 21) - 1);
      int t = r >> 10, c = r & 1023;
      src = (t < 1024) ? memory + ((size_t)b << 20) + (t << 10) + c
                       : key + ((size_t)b << 20) + ((t - 1024) << 10) + c;
      dst = kcat + i;
    } else if (g < g1) { i = (g - g0) * 4; src = query + i; dst = qbf + i; }
    else if (g < g2)   { i = (g - g1) * 4; src = pos + i;   dst = posb + i; }
    else if (g < g3)   { i = (g - g2) * 4; src = Wk + i;    dst = wkb + i; }
    else if (g < g4)   { i = (g - g3) * 4; src = Wv + i;    dst = wvb + i; }
    else if (g < g5)   { i = (g - g4) * 4; src = Wq + i;    dst = wqb + i; }
    else if (g < g6)   { i = (g - g5) * 4; src = Wp + i;    dst = wpb + i; }
    else if (g < g7)   { i = (g - g6) * 4; src = Wo + i;    dst = wob + i; }
    else {
      i = (g - g7) * 4;
      const int4 mv = *(const int4*)(mask + i);
      const unsigned int nm = f2bf(-1.4426950e30f);   // -1e30 * log2(e)
      uint2 o;
      o.x = (mv.x ? 0u : nm) | ((mv.y ? 0u : nm) << 16);
      o.y = (mv.z ? 0u : nm) | ((mv.w ? 0u : nm) << 16);
      *(uint2*)(mkb + i) = o;
      continue;
    }
    const float4 v = *(const float4*)src;
    uint2 o;
    o.x = cvtpk(v.x, v.y);
    o.y = cvtpk(v.z, v.w);
    *(uint2*)dst = o;
  }
}

// ------------- shared GEMM core: 128x128 bf16 tile, acc in regs -------------
#define GEMM_CORE() \
  f32x4 acc[4][4] = {}; \
  { \
    bf16x8 ra0 = *(const bf16x8*)Ap0; \
    bf16x8 ra1 = *(const bf16x8*)Ap1; \
    bf16x8 rb0 = *(const bf16x8*)Bp0; \
    bf16x8 rb1 = *(const bf16x8*)Bp1; \
    for (int kt = 0; kt < 32; ++kt) { \
      *(bf16x8*)(sA + swA0) = ra0; \
      *(bf16x8*)(sA + swA1) = ra1; \
      *(bf16x8*)(sB + swA0) = rb0; \
      *(bf16x8*)(sB + swA1) = rb1; \
      __syncthreads(); \
      if (kt + 1 < 32) { \
        const int o = (kt + 1) * 32; \
        ra0 = *(const bf16x8*)(Ap0 + o); \
        ra1 = *(const bf16x8*)(Ap1 + o); \
        rb0 = *(const bf16x8*)(Bp0 + o); \
        rb1 = *(const bf16x8*)(Bp1 + o); \
      } \
      bf16x8 af[4], bfr[4]; \
      _Pragma("unroll") \
      for (int mi = 0; mi < 4; ++mi) { \
        int row = wm + mi * 16 + l15; \
        af[mi] = *(const bf16x8*)(sA + row * 32 + ((l4 ^ ((row >> 1) & 3)) * 8)); \
      } \
      _Pragma("unroll") \
      for (int ni = 0; ni < 4; ++ni) { \
        int row = wn + ni * 16 + l15; \
        bfr[ni] = *(const bf16x8*)(sB + row * 32 + ((l4 ^ ((row >> 1) & 3)) * 8)); \
      } \
      _Pragma("unroll") \
      for (int mi = 0; mi < 4; ++mi) \
        _Pragma("unroll") \
        for (int ni = 0; ni < 4; ++ni) \
          acc[mi][ni] = mfma16(af[mi], bfr[ni], acc[mi][ni]); \
      __syncthreads(); \
    } \
  }

#define GEMM_PTRS(Asrc, Bsrc) \
  const unsigned short* Ap0 = Asrc + (size_t)(bm + am0) * 1024 + as0 * 8; \
  const unsigned short* Ap1 = Asrc + (size_t)(bm + am1) * 1024 + as1 * 8; \
  const unsigned short* Bp0 = Bsrc + (size_t)(bn + am0) * 1024 + as0 * 8; \
  const unsigned short* Bp1 = Bsrc + (size_t)(bn + am1) * 1024 + as1 * 8;

#define GEMM_IDX() \
  __shared__ unsigned short sA[128 * 32]; \
  __shared__ unsigned short sB[128 * 32]; \
  const int tid = threadIdx.x; \
  const int lane = tid & 63; \
  const int wid = tid >> 6; \
  const int wm = (wid >> 1) * 64, wn = (wid & 1) * 64; \
  const int l15 = lane & 15, l4 = lane >> 4; \
  const int am0 = tid >> 2, as0 = tid & 3; \
  const int am1 = (tid + 256) >> 2, as1 = (tid + 256) & 3; \
  const int swA0 = am0 * 32 + ((as0 ^ ((am0 >> 1) & 3)) * 8); \
  const int swA1 = am1 * 32 + ((as1 ^ ((am1 >> 1) & 3)) * 8);

// ALL projections (K, V, q+u/q+v, pos) in ONE 768-block launch.
// id<512: kv (A=kcat[4096], B=[Wk;Wv][2048]); id<640: q; else: pos.
__global__ __launch_bounds__(256, 2) void gemm_proj(
    const unsigned short* __restrict__ kcat, const unsigned short* __restrict__ qry,
    const unsigned short* __restrict__ posb,
    const unsigned short* __restrict__ wkv, const unsigned short* __restrict__ wqb,
    const unsigned short* __restrict__ wpb,
    const float* __restrict__ bk, const float* __restrict__ bv,
    const float* __restrict__ bq, const float* __restrict__ bp,
    const float* __restrict__ uvec, const float* __restrict__ vvec,
    unsigned short* __restrict__ kpk, unsigned short* __restrict__ vpk,
    unsigned short* __restrict__ qupk, unsigned short* __restrict__ qvpk,
    unsigned short* __restrict__ ppk)
{
  GEMM_IDX()
  const int id = blockIdx.x;
  int bm, bn, mode;
  const unsigned short *A, *Bw;
  if (id < 512)      { A = kcat; Bw = wkv; bm = (id >> 4) * 128; bn = (id & 15) * 128; mode = 0; }
  else if (id < 640) { const int t = id - 512; A = qry;  Bw = wqb; bm = (t >> 3) * 128; bn = (t & 7) * 128; mode = 1; }
  else               { const int t = id - 640; A = posb; Bw = wpb; bm = (t >> 3) * 128; bn = (t & 7) * 128; mode = 2; }
  GEMM_PTRS(A, Bw)
  GEMM_CORE()
  #pragma unroll
  for (int mi = 0; mi < 4; ++mi) {
    #pragma unroll
    for (int ni = 0; ni < 4; ++ni) {
      const int col = bn + wn + ni * 16 + l15;
      #pragma unroll
      for (int j = 0; j < 4; ++j) {
        const int row = bm + wm + mi * 16 + l4 * 4 + j;
        if (mode == 0) {
          const bool isK = col < 1024;
          const int cc = col & 1023;
          const float cv = acc[mi][ni][j] + (isK ? bk[cc] : bv[cc]);
          const int bI = row >> 11;
          const int t = row & 2047;
          const int bh2 = bI * NH + (cc >> 6);
          if (isK) {
            const size_t o = ((((size_t)bh2 * 128 + (t >> 4)) * 8 +
                              ((cc & 63) >> 3)) * 16 + (t & 15)) * 8 + (cc & 7);
            kpk[o] = f2bf(cv);
          } else {
            const int dk = cc & 63;
            const size_t o = (((((size_t)bh2 * 4 + (dk >> 4)) * 64 + (t >> 5)) * 4 +
                              ((t >> 3) & 3)) * 16 + (dk & 15)) * 8 + (t & 7);
            vpk[o] = f2bf(cv);
          }
        } else if (mode == 1) {
          const float cv = acc[mi][ni][j] + bq[col];
          const int bI = row >> 10;
          const int t = row & 1023;
          const int bh2 = bI * NH + (col >> 6);
          const size_t o = ((((size_t)bh2 * 64 + (t >> 4)) * 8 +
                            ((col & 63) >> 3)) * 16 + (t & 15)) * 8 + (col & 7);
          qupk[o] = f2bf(cv + uvec[col]);
          qvpk[o] = f2bf(cv + vvec[col]);
        } else {
          const float cv = acc[mi][ni][j] + bp[col];
          const int t = row;                  // single 2048-row batch
          const int h2 = col >> 6;
          const size_t o = ((((size_t)h2 * 128 + (t >> 4)) * 8 +
                            ((col & 63) >> 3)) * 16 + (t & 15)) * 8 + (col & 7);
          ppk[o] = f2bf(cv);
        }
      }
    }
  }
}

// final projection: fp32 row-major out. 64x128 tiles -> 256 blocks fills all
// 256 CUs (old 128x128 grid had only 128 blocks = half the machine idle).
__global__ __launch_bounds__(256, 2) void gemm_out(
    const unsigned short* __restrict__ A, const unsigned short* __restrict__ Bw,
    const float* __restrict__ bias, float* __restrict__ outf)
{
  __shared__ unsigned short sA[64 * 32];
  __shared__ unsigned short sB[128 * 32];
  const int tid = threadIdx.x;
  const int lane = tid & 63;
  const int wid = tid >> 6;
  const int wm = (wid & 1) * 32, wn = (wid >> 1) * 64;
  const int l15 = lane & 15, l4 = lane >> 4;
  const int bm = blockIdx.y * 64, bn = blockIdx.x * 128;
  const int amA = tid >> 2, asA = tid & 3;          // A: 64x32, 1 bf16x8/thread
  const unsigned short* ApA = A + (size_t)(bm + amA) * 1024 + asA * 8;
  const int swAA = amA * 32 + ((asA ^ ((amA >> 1) & 3)) * 8);
  const int am0 = tid >> 2, as0 = tid & 3;          // B: 128x32, 2/thread
  const int am1 = (tid + 256) >> 2, as1 = (tid + 256) & 3;
  const unsigned short* Bp0 = Bw + (size_t)(bn + am0) * 1024 + as0 * 8;
  const unsigned short* Bp1 = Bw + (size_t)(bn + am1) * 1024 + as1 * 8;
  const int swB0 = am0 * 32 + ((as0 ^ ((am0 >> 1) & 3)) * 8);
  const int swB1 = am1 * 32 + ((as1 ^ ((am1 >> 1) & 3)) * 8);

  f32x4 acc[2][4] = {};
  bf16x8 raA = *(const bf16x8*)ApA;
  bf16x8 rb0 = *(const bf16x8*)Bp0;
  bf16x8 rb1 = *(const bf16x8*)Bp1;
  for (int kt = 0; kt < 32; ++kt) {
    *(bf16x8*)(sA + swAA) = raA;
    *(bf16x8*)(sB + swB0) = rb0;
    *(bf16x8*)(sB + swB1) = rb1;
    __syncthreads();
    if (kt + 1 < 32) {
      const int o = (kt + 1) * 32;
      raA = *(const bf16x8*)(ApA + o);
      rb0 = *(const bf16x8*)(Bp0 + o);
      rb1 = *(const bf16x8*)(Bp1 + o);
    }
    bf16x8 af[2], bfr[4];
    #pragma unroll
    for (int mi = 0; mi < 2; ++mi) {
      int row = wm + mi * 16 + l15;
      af[mi] = *(const bf16x8*)(sA + row * 32 + ((l4 ^ ((row >> 1) & 3)) * 8));
    }
    #pragma unroll
    for (int ni = 0; ni < 4; ++ni) {
      int row = wn + ni * 16 + l15;
      bfr[ni] = *(const bf16x8*)(sB + row * 32 + ((l4 ^ ((row >> 1) & 3)) * 8));
    }
    #pragma unroll
    for (int mi = 0; mi < 2; ++mi)
      #pragma unroll
      for (int ni = 0; ni < 4; ++ni)
        acc[mi][ni] = mfma16(af[mi], bfr[ni], acc[mi][ni]);
    __syncthreads();
  }
  #pragma unroll
  for (int mi = 0; mi < 2; ++mi) {
    #pragma unroll
    for (int ni = 0; ni < 4; ++ni) {
      const int col = bn + wn + ni * 16 + l15;
      const float bval = bias[col];
      #pragma unroll
      for (int j = 0; j < 4; ++j) {
        const int row = bm + wm + mi * 16 + l4 * 4 + j;
        outf[(size_t)row * 1024 + col] = acc[mi][ni][j] + bval;
      }
    }
  }
}

// ---------------- fused scores + rel_shift + softmax + aw write + PV ----------------
// 16 q-rows/block, 16 waves, 2 blocks/CU -> 32 waves/CU. 64-VGPR budget;
// P1/P2 unroll 2 caps hoisted loads (R11: unroll-8 spilled); P5a/P5b deeper.
// P5a stashes 1/den per row in LDS; P5b multiplies (no re-reduce, no divide).
__global__ __launch_bounds__(1024, 8) void attn_fused(
    const unsigned short* __restrict__ qupk, const unsigned short* __restrict__ qvpk,
    const unsigned short* __restrict__ kpk, const unsigned short* __restrict__ ppk,
    const unsigned short* __restrict__ vpk, const unsigned short* __restrict__ mkb,
    float* __restrict__ awout, unsigned short* __restrict__ cvb)
{
  __shared__ unsigned short sbd[16 * 2048];   // 64 KB: BD -> p (bf16)
  __shared__ float sred0[16][16];             // per-wave row sums
  __shared__ float spv[3][4][16][16];         // split-K partials (kh=1..3)
  __shared__ float sdeni[16];                 // 1/den per row (written in P5a)
  const int tid = threadIdx.x;
  const int lane = tid & 63;
  const int w = tid >> 6;                      // 0..15
  const int l15 = lane & 15, l4 = lane >> 4;

  const int wg = blockIdx.x;                   // XCD-grouped, bh interleaved
  const int xcd = wg & 7, idx = wg >> 3;
  const int bh = xcd * 4 + (idx & 3);
  const int tI = idx >> 2;                     // 0..63
  const int I0 = tI * 16;
  const int b = bh >> 4, h = bh & 15;

  // ---- P1: BD via MFMA, scatter-written through the rel_shift mapping ----
  {
    const unsigned short* qvt = qvpk + ((size_t)bh * 64 + tI) * 1024;
    bf16x8 a0 = *(const bf16x8*)(qvt + l4 * 128 + l15 * 8);
    bf16x8 a1 = *(const bf16x8*)(qvt + (4 + l4) * 128 + l15 * 8);
    const unsigned short* ppk_h = ppk + (size_t)h * 131072;
    #pragma unroll 2
    for (int nj = 0; nj < 8; ++nj) {
      const int tile = w * 8 + nj;             // 0..127
      const unsigned short* pt = ppk_h + (size_t)tile * 1024;
      bf16x8 b0 = *(const bf16x8*)(pt + l4 * 128 + l15 * 8);
      bf16x8 b1 = *(const bf16x8*)(pt + (4 + l4) * 128 + l15 * 8);
      f32x4 c = {0.f, 0.f, 0.f, 0.f};
      c = mfma16(a0, b0, c);
      c = mfma16(a1, b1, c);
      const int jj = tile * 16 + l15;
      #pragma unroll
      for (int j = 0; j < 4; ++j) {
        const int rl = l4 * 4 + j;
        const int r = I0 + rl;
        int dst, jp;
        if (jj >= 1023 - r) { dst = rl;     jp = jj + r - 1023; }  // tail part
        else                { dst = rl - 1; jp = jj + r + 1025; }  // wrap part
        if (dst >= 0) sbd[swz(dst, jp)] = (unsigned short)(fbits(c[j]) >> 16);
      }
    }
    // extra BD row (I0+16) feeds last output row's wrap region; 4 tiles/wave
    if (I0 <= 1006) {
      const unsigned short* qvt2 = qvpk + ((size_t)bh * 64 + tI + 1) * 1024;
      bf16x8 a0e = *(const bf16x8*)(qvt2 + l4 * 128 + l15 * 8);
      bf16x8 a1e = *(const bf16x8*)(qvt2 + (4 + l4) * 128 + l15 * 8);
      #pragma unroll 2
      for (int nj = 0; nj < 4; ++nj) {
        const int tile = w * 4 + nj;           // 0..63
        const unsigned short* pt = ppk_h + (size_t)tile * 1024;
        bf16x8 b0 = *(const bf16x8*)(pt + l4 * 128 + l15 * 8);
        bf16x8 b1 = *(const bf16x8*)(pt + (4 + l4) * 128 + l15 * 8);
        f32x4 c = {0.f, 0.f, 0.f, 0.f};
        c = mfma16(a0e, b0, c);
        c = mfma16(a1e, b1, c);
        const int jj = tile * 16 + l15;
        if (l4 == 0 && jj <= 1006 - I0)
          sbd[swz(15, jj + I0 + 1041)] = (unsigned short)(fbits(c[0]) >> 16);
      }
    }
    if (tid < 16) {   // the zero column injected by the pad/reshape trick
      const int jp = I0 + tid + 1025;
      if (jp < 2048) sbd[swz(tid, jp)] = 0;
    }
  }
  __syncthreads();

  // ---- P2: AC (swapped MFMA) + BD + mask + 2^x -> p in place, row sums ----
  {
    const unsigned short* qut = qupk + ((size_t)bh * 64 + tI) * 1024;
    bf16x8 a0 = *(const bf16x8*)(qut + l4 * 128 + l15 * 8);
    bf16x8 a1 = *(const bf16x8*)(qut + (4 + l4) * 128 + l15 * 8);
    const unsigned short* kpk_b = kpk + (size_t)bh * 131072;
    const unsigned short* mrow = mkb + ((size_t)b * QL + I0 + l15) * TTOT;
    const int rowbyte = l15 * 4096;            // this thread's q-row = l15
    const int sws = (l15 & 7) << 4;
    float sm = 0.f;
    #pragma unroll 2
    for (int nj = 0; nj < 8; ++nj) {
      const int tile = w * 8 + nj;             // 0..127
      const unsigned short* kt = kpk_b + (size_t)tile * 1024;
      bf16x8 b0 = *(const bf16x8*)(kt + l4 * 128 + l15 * 8);
      bf16x8 b1 = *(const bf16x8*)(kt + (4 + l4) * 128 + l15 * 8);
      f32x4 c = {0.f, 0.f, 0.f, 0.f};
      c = mfma16(b0, a0, c);                   // swapped: rows=K pos, cols=q rows
      c = mfma16(b1, a1, c);
      const int jp0 = tile * 16 + l4 * 4;
      char* sp = (char*)sbd + rowbyte + ((jp0 * 2) ^ sws);
      const bf16x4 bd4 = *(const bf16x4*)sp;
      const bf16x4 m4 = *(const bf16x4*)(mrow + jp0);
      float p[4];
      #pragma unroll
      for (int j = 0; j < 4; ++j) {
        // s*log2e = (c+bd) * (0.125*log2e) + m2   (m2 pre-scaled by log2e)
        const float s2 = fmaf(c[j] + bf2f((unsigned short)bd4[j]), 0.18033688f,
                              bf2f((unsigned short)m4[j]));
        p[j] = exp2_hw(s2);
        sm += p[j];
      }
      uint2 pw;   // truncating pack
      pw.x = (fbits(p[1]) & 0xffff0000u) | (fbits(p[0]) >> 16);
      pw.y = (fbits(p[3]) & 0xffff0000u) | (fbits(p[2]) >> 16);
      *(uint2*)sp = pw;
    }
    sm += __shfl_xor(sm, 16, 64);
    sm += __shfl_xor(sm, 32, 64);
    if (l4 == 0) sred0[w][l15] = sm;
  }
  __syncthreads();

  // ---- P5a: aw fp32 write, normalized on the fly (one row per wave) ----
  {
    const int r = w;                           // 0..15
    float den = sred0[0][r];
    #pragma unroll
    for (int ww = 1; ww < 16; ++ww) den += sred0[ww][r];
    const float rinv = 1.0f / den;
    if (lane == 0) sdeni[r] = rinv;            // consumed by P5b (after barrier)
    float* awb = awout + ((size_t)bh * QL + I0 + r) * TTOT;
    const int sws = (r & 7) << 4;
    #pragma unroll
    for (int q = 0; q < 4; ++q) {
      const int X = q * 1024 + lane * 16;               // true column byte
      bf16x8 vv = *(const bf16x8*)((const char*)sbd + r * 4096 + (X ^ sws));
      f32x4 lo, hi;
      #pragma unroll
      for (int k = 0; k < 4; ++k) {
        lo[k] = bf2f((unsigned short)vv[k]) * rinv;
        hi[k] = bf2f((unsigned short)vv[k + 4]) * rinv;
      }
      float* dp = awb + (X >> 1);                       // unswizzled destination
      *(f32x4*)dp = lo;
      *(f32x4*)(dp + 4) = hi;
    }
  }

  // ---- P5b: PV on p (packed V), 4-way split-K across waves; normalize last ----
  {
    const int dc = w & 3, kh = w >> 2;         // kh 0..3
    const unsigned short* vb = vpk + ((size_t)(bh * 4 + dc) * 64) * 512;
    const int sws = (l15 & 7) << 4;
    const int rowbyte = l15 * 4096;
    f32x4 pv = {0.f, 0.f, 0.f, 0.f};
    #pragma unroll 4
    for (int ks = kh * 16; ks < kh * 16 + 16; ++ks) {
      bf16x8 a = *(const bf16x8*)((const char*)sbd +
                  (rowbyte + ((ks * 64 + l4 * 16) ^ sws)));
      bf16x8 vvf = *(const bf16x8*)(vb + ks * 512 + lane * 8);
      pv = mfma16(a, vvf, pv);
    }
    if (kh) {
      #pragma unroll
      for (int j = 0; j < 4; ++j) spv[kh - 1][dc][l4 * 4 + j][l15] = pv[j];
    }
    __syncthreads();                           // orders spv AND sdeni
    if (!kh) {
      const size_t obase = ((size_t)b * QL + I0 + l4 * 4) * 1024 + h * 64 + dc * 16 + l15;
      #pragma unroll
      for (int j = 0; j < 4; ++j) {
        const int rl = l4 * 4 + j;
        const float o = (pv[j] + spv[0][dc][rl][l15] + spv[1][dc][rl][l15] +
                         spv[2][dc][rl][l15]) * sdeni[rl];
        cvb[obase + (size_t)j * 1024] = f2bf(o);
      }
    }
  }
}

extern "C" void kernel_launch(void* const* d_in, const int* in_sizes, int n_in,
                              void* d_out, int out_size, void* d_ws, size_t ws_size,
                              hipStream_t stream) {
  (void)in_sizes; (void)n_in; (void)out_size; (void)ws_size;
  const float* key    = (const float*)d_in[0];
  const float* query  = (const float*)d_in[1];
  const float* memory = (const float*)d_in[2];
  const float* pos    = (const float*)d_in[3];
  const int*   mask   = (const int*)d_in[4];
  const float* u      = (const float*)d_in[5];
  const float* v      = (const float*)d_in[6];
  const float* Wk     = (const float*)d_in[7];
  const float* bk     = (const float*)d_in[8];
  const float* Wv     = (const float*)d_in[9];
  const float* bv     = (const float*)d_in[10];
  const float* Wq     = (const float*)d_in[11];
  const float* bq     = (const float*)d_in[12];
  const float* Wp     = (const float*)d_in[13];
  const float* bp     = (const float*)d_in[14];
  const float* Wo     = (const float*)d_in[15];
  const float* bo     = (const float*)d_in[16];

  float* outCV = (float*)d_out;
  float* outAW = outCV + 2097152;

  char* ws = (char*)d_ws;
  const size_t MB = (size_t)1 << 20;
  unsigned short* kpk  = (unsigned short*)(ws + 0);        // packed K     8MB
  unsigned short* vpk  = (unsigned short*)(ws + 8 * MB);   // packed V     8MB
  unsigned short* qupk = (unsigned short*)(ws + 16 * MB);  // packed q+u   4MB
  unsigned short* qvpk = (unsigned short*)(ws + 20 * MB);  // packed q+v   4MB
  unsigned short* ppk  = (unsigned short*)(ws + 24 * MB);  // packed pos   4MB
  unsigned short* cvb  = (unsigned short*)(ws + 28 * MB);  // [b*Q][1024]  4MB
  unsigned short* kcat = (unsigned short*)(ws + 32 * MB);  // [b][t][1024] 8MB
  unsigned short* qry  = (unsigned short*)(ws + 40 * MB);  // 4MB
  unsigned short* posb = (unsigned short*)(ws + 44 * MB);  // 4MB
  unsigned short* wkb  = (unsigned short*)(ws + 48 * MB);  // 2MB (contig with wvb!)
  unsigned short* wvb  = (unsigned short*)(ws + 50 * MB);  // 2MB
  unsigned short* wqb  = (unsigned short*)(ws + 52 * MB);
  unsigned short* wpb  = (unsigned short*)(ws + 54 * MB);
  unsigned short* wob  = (unsigned short*)(ws + 56 * MB);
  unsigned short* mkb  = (unsigned short*)(ws + 58 * MB);  // row-major mask 8MB

  convert_all<<<2048, 256, 0, stream>>>(key, query, memory, pos, mask,
      Wk, Wv, Wq, Wp, Wo, kcat, qry, posb, wkb, wvb, wqb, wpb, wob, mkb);

  // ALL projections in one 768-block launch (kv 512 + q 128 + pos 128)
  gemm_proj<<<768, 256, 0, stream>>>(kcat, qry, posb, wkb, wqb, wpb,
      bk, bv, bq, bp, u, v, kpk, vpk, qupk, qvpk, ppk);

  attn_fused<<<2048, 1024, 0, stream>>>(qupk, qvpk, kpk, ppk, vpk, mkb,
      outAW, cvb);

  gemm_out<<<dim3(8, 32), 256, 0, stream>>>(cvb, wob, bo, outCV);
}

// Round 16
// 231.323 us; speedup vs baseline: 1.4422x; 1.0043x over previous
//
#include <hip/hip_runtime.h>

using bf16x8 = __attribute__((ext_vector_type(8))) short;
using bf16x4 = __attribute__((ext_vector_type(4))) short;
using f32x4  = __attribute__((ext_vector_type(4))) float;

#define NH    16
#define DKH   64
#define TTOT  2048
#define QL    1024

__device__ __forceinline__ float bf2f(unsigned short u) {
  union { unsigned int i; float f; } c; c.i = ((unsigned int)u) << 16; return c.f;
}
__device__ __forceinline__ unsigned short f2bf(float f) {
  union { float f; unsigned int i; } c; c.f = f;
  unsigned int x = c.i;
  x += 0x7fffu + ((x >> 16) & 1u);
  return (unsigned short)(x >> 16);
}
// truncating f32->bf16 (1 op); used where 0.4% rel err is provably harmless
__device__ __forceinline__ unsigned int fbits(float f) {
  union { float f; unsigned int i; } c; c.f = f; return c.i;
}
// HW packed f32->bf16. ORDER-INSENSITIVE uses only (R9 post-mortem):
// applied identically to both GEMM operands, a pairwise K-permutation cancels.
__device__ __forceinline__ unsigned int cvtpk(float lo, float hi) {
  unsigned int r;
  asm("v_cvt_pk_bf16_f32 %0, %1, %2" : "=v"(r) : "v"(lo), "v"(hi));
  return r;
}
// native base-2 exp (v_exp_f32 computes 2^x); pure-VALU asm, dep-tracked
__device__ __forceinline__ float exp2_hw(float x) {
  float r;
  asm("v_exp_f32 %0, %1" : "=v"(r) : "v"(x));
  return r;
}
// XOR swizzle inside each row (byte bits 4..6 ^= row&7) for 16x2048 bf16 LDS rows
__device__ __forceinline__ int swz(int r, int c) {
  return r * 2048 + ((((c << 1) ^ ((r & 7) << 4))) >> 1);
}
__device__ __forceinline__ f32x4 mfma16(bf16x8 a, bf16x8 b, f32x4 c) {
  return __builtin_amdgcn_mfma_f32_16x16x32_bf16(a, b, c, 0, 0, 0);
}

// ---------------- convert fp32 inputs -> bf16 workspace (vectorized x4) ----------------
// Mask bias stored PRE-SCALED by log2(e) so P2 can use 2^x directly.
__global__ void convert_all(
    const float* __restrict__ key, const float* __restrict__ query,
    const float* __restrict__ memory, const float* __restrict__ pos,
    const int* __restrict__ mask,
    const float* __restrict__ Wk, const float* __restrict__ Wv,
    const float* __restrict__ Wq, const float* __restrict__ Wp,
    const float* __restrict__ Wo,
    unsigned short* __restrict__ kcat, unsigned short* __restrict__ qbf,
    unsigned short* __restrict__ posb,
    unsigned short* __restrict__ wkb, unsigned short* __restrict__ wvb,
    unsigned short* __restrict__ wqb, unsigned short* __restrict__ wpb,
    unsigned short* __restrict__ wob, unsigned short* __restrict__ mkb)
{
  const int g0 = 1048576;            // kcat /4
  const int g1 = g0 + 524288;        // query
  const int g2 = g1 + 524288;        // pos
  const int g3 = g2 + 262144;        // Wk
  const int g4 = g3 + 262144;        // Wv
  const int g5 = g4 + 262144;        // Wq
  const int g6 = g5 + 262144;        // Wp
  const int g7 = g6 + 262144;        // Wo
  const int g8 = g7 + 1048576;       // mask
  for (int g = blockIdx.x * blockDim.x + threadIdx.x; g < g8;
       g += gridDim.x * blockDim.x) {
    const float* src = nullptr;
    unsigned short* dst = nullptr;
    int i;
    if (g < g0) {
      i = g * 4;
      int b = i >> 21, r = i & ((1 << 21) - 1);
      int t = r >> 10, c = r & 1023;
      src = (t < 1024) ? memory + ((size_t)b << 20) + (t << 10) + c
                       : key + ((size_t)b << 20) + ((t - 1024) << 10) + c;
      dst = kcat + i;
    } else if (g < g1) { i = (g - g0) * 4; src = query + i; dst = qbf + i; }
    else if (g < g2)   { i = (g - g1) * 4; src = pos + i;   dst = posb + i; }
    else if (g < g3)   { i = (g - g2) * 4; src = Wk + i;    dst = wkb + i; }
    else if (g < g4)   { i = (g - g3) * 4; src = Wv + i;    dst = wvb + i; }
    else if (g < g5)   { i = (g - g4) * 4; src = Wq + i;    dst = wqb + i; }
    else if (g < g6)   { i = (g - g5) * 4; src = Wp + i;    dst = wpb + i; }
    else if (g < g7)   { i = (g - g6) * 4; src = Wo + i;    dst = wob + i; }
    else {
      i = (g - g7) * 4;
      const int4 mv = *(const int4*)(mask + i);
      const unsigned int nm = f2bf(-1.4426950e30f);   // -1e30 * log2(e)
      uint2 o;
      o.x = (mv.x ? 0u : nm) | ((mv.y ? 0u : nm) << 16);
      o.y = (mv.z ? 0u : nm) | ((mv.w ? 0u : nm) << 16);
      *(uint2*)(mkb + i) = o;
      continue;
    }
    const float4 v = *(const float4*)src;
    uint2 o;
    o.x = cvtpk(v.x, v.y);
    o.y = cvtpk(v.z, v.w);
    *(uint2*)dst = o;
  }
}

// ------------- shared GEMM core: 128x128 bf16 tile, acc in regs -------------
#define GEMM_CORE() \
  f32x4 acc[4][4] = {}; \
  { \
    bf16x8 ra0 = *(const bf16x8*)Ap0; \
    bf16x8 ra1 = *(const bf16x8*)Ap1; \
    bf16x8 rb0 = *(const bf16x8*)Bp0; \
    bf16x8 rb1 = *(const bf16x8*)Bp1; \
    for (int kt = 0; kt < 32; ++kt) { \
      *(bf16x8*)(sA + swA0) = ra0; \
      *(bf16x8*)(sA + swA1) = ra1; \
      *(bf16x8*)(sB + swA0) = rb0; \
      *(bf16x8*)(sB + swA1) = rb1; \
      __syncthreads(); \
      if (kt + 1 < 32) { \
        const int o = (kt + 1) * 32; \
        ra0 = *(const bf16x8*)(Ap0 + o); \
        ra1 = *(const bf16x8*)(Ap1 + o); \
        rb0 = *(const bf16x8*)(Bp0 + o); \
        rb1 = *(const bf16x8*)(Bp1 + o); \
      } \
      bf16x8 af[4], bfr[4]; \
      _Pragma("unroll") \
      for (int mi = 0; mi < 4; ++mi) { \
        int row = wm + mi * 16 + l15; \
        af[mi] = *(const bf16x8*)(sA + row * 32 + ((l4 ^ ((row >> 1) & 3)) * 8)); \
      } \
      _Pragma("unroll") \
      for (int ni = 0; ni < 4; ++ni) { \
        int row = wn + ni * 16 + l15; \
        bfr[ni] = *(const bf16x8*)(sB + row * 32 + ((l4 ^ ((row >> 1) & 3)) * 8)); \
      } \
      _Pragma("unroll") \
      for (int mi = 0; mi < 4; ++mi) \
        _Pragma("unroll") \
        for (int ni = 0; ni < 4; ++ni) \
          acc[mi][ni] = mfma16(af[mi], bfr[ni], acc[mi][ni]); \
      __syncthreads(); \
    } \
  }

#define GEMM_PTRS(Asrc, Bsrc) \
  const unsigned short* Ap0 = Asrc + (size_t)(bm + am0) * 1024 + as0 * 8; \
  const unsigned short* Ap1 = Asrc + (size_t)(bm + am1) * 1024 + as1 * 8; \
  const unsigned short* Bp0 = Bsrc + (size_t)(bn + am0) * 1024 + as0 * 8; \
  const unsigned short* Bp1 = Bsrc + (size_t)(bn + am1) * 1024 + as1 * 8;

#define GEMM_IDX() \
  __shared__ unsigned short sA[128 * 32]; \
  __shared__ unsigned short sB[128 * 32]; \
  const int tid = threadIdx.x; \
  const int lane = tid & 63; \
  const int wid = tid >> 6; \
  const int wm = (wid >> 1) * 64, wn = (wid & 1) * 64; \
  const int l15 = lane & 15, l4 = lane >> 4; \
  const int am0 = tid >> 2, as0 = tid & 3; \
  const int am1 = (tid + 256) >> 2, as1 = (tid + 256) & 3; \
  const int swA0 = am0 * 32 + ((as0 ^ ((am0 >> 1) & 3)) * 8); \
  const int swA1 = am1 * 32 + ((as1 ^ ((am1 >> 1) & 3)) * 8);

// ALL projections (K, V, q+u/q+v, pos) in ONE 768-block launch.
// id<512: kv (A=kcat[4096], B=[Wk;Wv][2048]); id<640: q; else: pos.
__global__ __launch_bounds__(256, 2) void gemm_proj(
    const unsigned short* __restrict__ kcat, const unsigned short* __restrict__ qry,
    const unsigned short* __restrict__ posb,
    const unsigned short* __restrict__ wkv, const unsigned short* __restrict__ wqb,
    const unsigned short* __restrict__ wpb,
    const float* __restrict__ bk, const float* __restrict__ bv,
    const float* __restrict__ bq, const float* __restrict__ bp,
    const float* __restrict__ uvec, const float* __restrict__ vvec,
    unsigned short* __restrict__ kpk, unsigned short* __restrict__ vpk,
    unsigned short* __restrict__ qupk, unsigned short* __restrict__ qvpk,
    unsigned short* __restrict__ ppk)
{
  GEMM_IDX()
  const int id = blockIdx.x;
  int bm, bn, mode;
  const unsigned short *A, *Bw;
  if (id < 512)      { A = kcat; Bw = wkv; bm = (id >> 4) * 128; bn = (id & 15) * 128; mode = 0; }
  else if (id < 640) { const int t = id - 512; A = qry;  Bw = wqb; bm = (t >> 3) * 128; bn = (t & 7) * 128; mode = 1; }
  else               { const int t = id - 640; A = posb; Bw = wpb; bm = (t >> 3) * 128; bn = (t & 7) * 128; mode = 2; }
  GEMM_PTRS(A, Bw)
  GEMM_CORE()
  #pragma unroll
  for (int mi = 0; mi < 4; ++mi) {
    #pragma unroll
    for (int ni = 0; ni < 4; ++ni) {
      const int col = bn + wn + ni * 16 + l15;
      #pragma unroll
      for (int j = 0; j < 4; ++j) {
        const int row = bm + wm + mi * 16 + l4 * 4 + j;
        if (mode == 0) {
          const bool isK = col < 1024;
          const int cc = col & 1023;
          const float cv = acc[mi][ni][j] + (isK ? bk[cc] : bv[cc]);
          const int bI = row >> 11;
          const int t = row & 2047;
          const int bh2 = bI * NH + (cc >> 6);
          if (isK) {
            const size_t o = ((((size_t)bh2 * 128 + (t >> 4)) * 8 +
                              ((cc & 63) >> 3)) * 16 + (t & 15)) * 8 + (cc & 7);
            kpk[o] = f2bf(cv);
          } else {
            const int dk = cc & 63;
            const size_t o = (((((size_t)bh2 * 4 + (dk >> 4)) * 64 + (t >> 5)) * 4 +
                              ((t >> 3) & 3)) * 16 + (dk & 15)) * 8 + (t & 7);
            vpk[o] = f2bf(cv);
          }
        } else if (mode == 1) {
          const float cv = acc[mi][ni][j] + bq[col];
          const int bI = row >> 10;
          const int t = row & 1023;
          const int bh2 = bI * NH + (col >> 6);
          const size_t o = ((((size_t)bh2 * 64 + (t >> 4)) * 8 +
                            ((col & 63) >> 3)) * 16 + (t & 15)) * 8 + (col & 7);
          qupk[o] = f2bf(cv + uvec[col]);
          qvpk[o] = f2bf(cv + vvec[col]);
        } else {
          const float cv = acc[mi][ni][j] + bp[col];
          const int t = row;                  // single 2048-row batch
          const int h2 = col >> 6;
          const size_t o = ((((size_t)h2 * 128 + (t >> 4)) * 8 +
                            ((col & 63) >> 3)) * 16 + (t & 15)) * 8 + (col & 7);
          ppk[o] = f2bf(cv);
        }
      }
    }
  }
}

// final projection: fp32 row-major out. 64x128 tiles -> 256 blocks fills all CUs.
__global__ __launch_bounds__(256, 2) void gemm_out(
    const unsigned short* __restrict__ A, const unsigned short* __restrict__ Bw,
    const float* __restrict__ bias, float* __restrict__ outf)
{
  __shared__ unsigned short sA[64 * 32];
  __shared__ unsigned short sB[128 * 32];
  const int tid = threadIdx.x;
  const int lane = tid & 63;
  const int wid = tid >> 6;
  const int wm = (wid & 1) * 32, wn = (wid >> 1) * 64;
  const int l15 = lane & 15, l4 = lane >> 4;
  const int bm = blockIdx.y * 64, bn = blockIdx.x * 128;
  const int amA = tid >> 2, asA = tid & 3;          // A: 64x32, 1 bf16x8/thread
  const unsigned short* ApA = A + (size_t)(bm + amA) * 1024 + asA * 8;
  const int swAA = amA * 32 + ((asA ^ ((amA >> 1) & 3)) * 8);
  const int am0 = tid >> 2, as0 = tid & 3;          // B: 128x32, 2/thread
  const int am1 = (tid + 256) >> 2, as1 = (tid + 256) & 3;
  const unsigned short* Bp0 = Bw + (size_t)(bn + am0) * 1024 + as0 * 8;
  const unsigned short* Bp1 = Bw + (size_t)(bn + am1) * 1024 + as1 * 8;
  const int swB0 = am0 * 32 + ((as0 ^ ((am0 >> 1) & 3)) * 8);
  const int swB1 = am1 * 32 + ((as1 ^ ((am1 >> 1) & 3)) * 8);

  f32x4 acc[2][4] = {};
  bf16x8 raA = *(const bf16x8*)ApA;
  bf16x8 rb0 = *(const bf16x8*)Bp0;
  bf16x8 rb1 = *(const bf16x8*)Bp1;
  for (int kt = 0; kt < 32; ++kt) {
    *(bf16x8*)(sA + swAA) = raA;
    *(bf16x8*)(sB + swB0) = rb0;
    *(bf16x8*)(sB + swB1) = rb1;
    __syncthreads();
    if (kt + 1 < 32) {
      const int o = (kt + 1) * 32;
      raA = *(const bf16x8*)(ApA + o);
      rb0 = *(const bf16x8*)(Bp0 + o);
      rb1 = *(const bf16x8*)(Bp1 + o);
    }
    bf16x8 af[2], bfr[4];
    #pragma unroll
    for (int mi = 0; mi < 2; ++mi) {
      int row = wm + mi * 16 + l15;
      af[mi] = *(const bf16x8*)(sA + row * 32 + ((l4 ^ ((row >> 1) & 3)) * 8));
    }
    #pragma unroll
    for (int ni = 0; ni < 4; ++ni) {
      int row = wn + ni * 16 + l15;
      bfr[ni] = *(const bf16x8*)(sB + row * 32 + ((l4 ^ ((row >> 1) & 3)) * 8));
    }
    #pragma unroll
    for (int mi = 0; mi < 2; ++mi)
      #pragma unroll
      for (int ni = 0; ni < 4; ++ni)
        acc[mi][ni] = mfma16(af[mi], bfr[ni], acc[mi][ni]);
    __syncthreads();
  }
  #pragma unroll
  for (int mi = 0; mi < 2; ++mi) {
    #pragma unroll
    for (int ni = 0; ni < 4; ++ni) {
      const int col = bn + wn + ni * 16 + l15;
      const float bval = bias[col];
      #pragma unroll
      for (int j = 0; j < 4; ++j) {
        const int row = bm + wm + mi * 16 + l4 * 4 + j;
        outf[(size_t)row * 1024 + col] = acc[mi][ni][j] + bval;
      }
    }
  }
}

// ---------------- fused scores + rel_shift + softmax + aw write + PV ----------------
// 16 q-rows/block, 16 waves, 2 blocks/CU -> 32 waves/CU. 64-VGPR budget;
// P1/P2 unroll 2 caps hoisted loads (R11 lesson). Branchless rel_shift:
// base = jj + r - 1023 in [-1023,2047]; wrap iff base<0; jp = base & 2047
// (adds 2048 exactly when negative); dst = rl + (base>>31).
__global__ __launch_bounds__(1024, 8) void attn_fused(
    const unsigned short* __restrict__ qupk, const unsigned short* __restrict__ qvpk,
    const unsigned short* __restrict__ kpk, const unsigned short* __restrict__ ppk,
    const unsigned short* __restrict__ vpk, const unsigned short* __restrict__ mkb,
    float* __restrict__ awout, unsigned short* __restrict__ cvb)
{
  __shared__ unsigned short sbd[16 * 2048];   // 64 KB: BD -> p (bf16)
  __shared__ float sred0[16][16];             // per-wave row sums
  __shared__ float spv[3][4][16][16];         // split-K partials (kh=1..3)
  __shared__ float sdeni[16];                 // 1/den per row (written in P5a)
  const int tid = threadIdx.x;
  const int lane = tid & 63;
  const int w = tid >> 6;                      // 0..15
  const int l15 = lane & 15, l4 = lane >> 4;

  const int wg = blockIdx.x;                   // XCD-grouped, bh interleaved
  const int xcd = wg & 7, idx = wg >> 3;
  const int bh = xcd * 4 + (idx & 3);
  const int tI = idx >> 2;                     // 0..63
  const int I0 = tI * 16;
  const int b = bh >> 4, h = bh & 15;

  // ---- P1: BD via MFMA, scatter-written through the rel_shift mapping ----
  {
    const unsigned short* qvt = qvpk + ((size_t)bh * 64 + tI) * 1024;
    bf16x8 a0 = *(const bf16x8*)(qvt + l4 * 128 + l15 * 8);
    bf16x8 a1 = *(const bf16x8*)(qvt + (4 + l4) * 128 + l15 * 8);
    const unsigned short* ppk_h = ppk + (size_t)h * 131072;
    const int rl0 = l4 * 4;
    #pragma unroll 2
    for (int nj = 0; nj < 8; ++nj) {
      const int tile = w * 8 + nj;             // 0..127
      const unsigned short* pt = ppk_h + (size_t)tile * 1024;
      bf16x8 b0 = *(const bf16x8*)(pt + l4 * 128 + l15 * 8);
      bf16x8 b1 = *(const bf16x8*)(pt + (4 + l4) * 128 + l15 * 8);
      f32x4 c = {0.f, 0.f, 0.f, 0.f};
      c = mfma16(a0, b0, c);
      c = mfma16(a1, b1, c);
      // base0 = jj + (I0 + rl0) - 1023; per j just +1
      int base = (tile * 16 + l15) + I0 + rl0 - 1023;
      #pragma unroll
      for (int j = 0; j < 4; ++j, ++base) {
        const int dst = rl0 + j + (base >> 31);     // rl or rl-1 (wrap)
        const int jp = base & 2047;                 // +2048 when wrap
        if (dst >= 0) sbd[swz(dst, jp)] = (unsigned short)(fbits(c[j]) >> 16);
      }
    }
    // extra BD row (I0+16) feeds last output row's wrap region; 4 tiles/wave
    if (I0 <= 1006) {
      const unsigned short* qvt2 = qvpk + ((size_t)bh * 64 + tI + 1) * 1024;
      bf16x8 a0e = *(const bf16x8*)(qvt2 + l4 * 128 + l15 * 8);
      bf16x8 a1e = *(const bf16x8*)(qvt2 + (4 + l4) * 128 + l15 * 8);
      #pragma unroll 2
      for (int nj = 0; nj < 4; ++nj) {
        const int tile = w * 4 + nj;           // 0..63
        const unsigned short* pt = ppk_h + (size_t)tile * 1024;
        bf16x8 b0 = *(const bf16x8*)(pt + l4 * 128 + l15 * 8);
        bf16x8 b1 = *(const bf16x8*)(pt + (4 + l4) * 128 + l15 * 8);
        f32x4 c = {0.f, 0.f, 0.f, 0.f};
        c = mfma16(a0e, b0, c);
        c = mfma16(a1e, b1, c);
        const int jj = tile * 16 + l15;
        if (l4 == 0 && jj <= 1006 - I0)
          sbd[swz(15, jj + I0 + 1041)] = (unsigned short)(fbits(c[0]) >> 16);
      }
    }
    if (tid < 16) {   // the zero column injected by the pad/reshape trick
      const int jp = I0 + tid + 1025;
      if (jp < 2048) sbd[swz(tid, jp)] = 0;
    }
  }
  __syncthreads();

  // ---- P2: AC (swapped MFMA) + BD + mask + 2^x -> p in place, row sums ----
  {
    const unsigned short* qut = qupk + ((size_t)bh * 64 + tI) * 1024;
    bf16x8 a0 = *(const bf16x8*)(qut + l4 * 128 + l15 * 8);
    bf16x8 a1 = *(const bf16x8*)(qut + (4 + l4) * 128 + l15 * 8);
    const unsigned short* kpk_b = kpk + (size_t)bh * 131072;
    const unsigned short* mrow = mkb + ((size_t)b * QL + I0 + l15) * TTOT;
    const int rowbyte = l15 * 4096;            // this thread's q-row = l15
    const int sws = (l15 & 7) << 4;
    float sm = 0.f;
    #pragma unroll 2
    for (int nj = 0; nj < 8; ++nj) {
      const int tile = w * 8 + nj;             // 0..127
      const unsigned short* kt = kpk_b + (size_t)tile * 1024;
      bf16x8 b0 = *(const bf16x8*)(kt + l4 * 128 + l15 * 8);
      bf16x8 b1 = *(const bf16x8*)(kt + (4 + l4) * 128 + l15 * 8);
      f32x4 c = {0.f, 0.f, 0.f, 0.f};
      c = mfma16(b0, a0, c);                   // swapped: rows=K pos, cols=q rows
      c = mfma16(b1, a1, c);
      const int jp0 = tile * 16 + l4 * 4;
      char* sp = (char*)sbd + rowbyte + ((jp0 * 2) ^ sws);
      const bf16x4 bd4 = *(const bf16x4*)sp;
      const bf16x4 m4 = *(const bf16x4*)(mrow + jp0);
      float p[4];
      #pragma unroll
      for (int j = 0; j < 4; ++j) {
        // s*log2e = (c+bd) * (0.125*log2e) + m2   (m2 pre-scaled by log2e)
        const float s2 = fmaf(c[j] + bf2f((unsigned short)bd4[j]), 0.18033688f,
                              bf2f((unsigned short)m4[j]));
        p[j] = exp2_hw(s2);
        sm += p[j];
      }
      uint2 pw;   // truncating pack
      pw.x = (fbits(p[1]) & 0xffff0000u) | (fbits(p[0]) >> 16);
      pw.y = (fbits(p[3]) & 0xffff0000u) | (fbits(p[2]) >> 16);
      *(uint2*)sp = pw;
    }
    sm += __shfl_xor(sm, 16, 64);
    sm += __shfl_xor(sm, 32, 64);
    if (l4 == 0) sred0[w][l15] = sm;
  }
  __syncthreads();

  // ---- P5a: aw fp32 write, normalized on the fly (one row per wave) ----
  {
    const int r = w;                           // 0..15
    float den = sred0[0][r];
    #pragma unroll
    for (int ww = 1; ww < 16; ++ww) den += sred0[ww][r];
    const float rinv = 1.0f / den;
    if (lane == 0) sdeni[r] = rinv;            // consumed by P5b (after barrier)
    float* awb = awout + ((size_t)bh * QL + I0 + r) * TTOT;
    const int sws = (r & 7) << 4;
    #pragma unroll
    for (int q = 0; q < 4; ++q) {
      const int X = q * 1024 + lane * 16;               // true column byte
      bf16x8 vv = *(const bf16x8*)((const char*)sbd + r * 4096 + (X ^ sws));
      f32x4 lo, hi;
      #pragma unroll
      for (int k = 0; k < 4; ++k) {
        lo[k] = bf2f((unsigned short)vv[k]) * rinv;
        hi[k] = bf2f((unsigned short)vv[k + 4]) * rinv;
      }
      float* dp = awb + (X >> 1);                       // unswizzled destination
      *(f32x4*)dp = lo;
      *(f32x4*)(dp + 4) = hi;
    }
  }

  // ---- P5b: PV on p (packed V), 4-way split-K across waves; normalize last ----
  {
    const int dc = w & 3, kh = w >> 2;         // kh 0..3
    const unsigned short* vb = vpk + ((size_t)(bh * 4 + dc) * 64) * 512;
    const int sws = (l15 & 7) << 4;
    const int rowbyte = l15 * 4096;
    f32x4 pv = {0.f, 0.f, 0.f, 0.f};
    #pragma unroll 4
    for (int ks = kh * 16; ks < kh * 16 + 16; ++ks) {
      bf16x8 a = *(const bf16x8*)((const char*)sbd +
                  (rowbyte + ((ks * 64 + l4 * 16) ^ sws)));
      bf16x8 vvf = *(const bf16x8*)(vb + ks * 512 + lane * 8);
      pv = mfma16(a, vvf, pv);
    }
    if (kh) {
      #pragma unroll
      for (int j = 0; j < 4; ++j) spv[kh - 1][dc][l4 * 4 + j][l15] = pv[j];
    }
    __syncthreads();                           // orders spv AND sdeni
    if (!kh) {
      const size_t obase = ((size_t)b * QL + I0 + l4 * 4) * 1024 + h * 64 + dc * 16 + l15;
      #pragma unroll
      for (int j = 0; j < 4; ++j) {
        const int rl = l4 * 4 + j;
        const float o = (pv[j] + spv[0][dc][rl][l15] + spv[1][dc][rl][l15] +
                         spv[2][dc][rl][l15]) * sdeni[rl];
        cvb[obase + (size_t)j * 1024] = f2bf(o);
      }
    }
  }
}

extern "C" void kernel_launch(void* const* d_in, const int* in_sizes, int n_in,
                              void* d_out, int out_size, void* d_ws, size_t ws_size,
                              hipStream_t stream) {
  (void)in_sizes; (void)n_in; (void)out_size; (void)ws_size;
  const float* key    = (const float*)d_in[0];
  const float* query  = (const float*)d_in[1];
  const float* memory = (const float*)d_in[2];
  const float* pos    = (const float*)d_in[3];
  const int*   mask   = (const int*)d_in[4];
  const float* u      = (const float*)d_in[5];
  const float* v      = (const float*)d_in[6];
  const float* Wk     = (const float*)d_in[7];
  const float* bk     = (const float*)d_in[8];
  const float* Wv     = (const float*)d_in[9];
  const float* bv     = (const float*)d_in[10];
  const float* Wq     = (const float*)d_in[11];
  const float* bq     = (const float*)d_in[12];
  const float* Wp     = (const float*)d_in[13];
  const float* bp     = (const float*)d_in[14];
  const float* Wo     = (const float*)d_in[15];
  const float* bo     = (const float*)d_in[16];

  float* outCV = (float*)d_out;
  float* outAW = outCV + 2097152;

  char* ws = (char*)d_ws;
  const size_t MB = (size_t)1 << 20;
  unsigned short* kpk  = (unsigned short*)(ws + 0);        // packed K     8MB
  unsigned short* vpk  = (unsigned short*)(ws + 8 * MB);   // packed V     8MB
  unsigned short* qupk = (unsigned short*)(ws + 16 * MB);  // packed q+u   4MB
  unsigned short* qvpk = (unsigned short*)(ws + 20 * MB);  // packed q+v   4MB
  unsigned short* ppk  = (unsigned short*)(ws + 24 * MB);  // packed pos   4MB
  unsigned short* cvb  = (unsigned short*)(ws + 28 * MB);  // [b*Q][1024]  4MB
  unsigned short* kcat = (unsigned short*)(ws + 32 * MB);  // [b][t][1024] 8MB
  unsigned short* qry  = (unsigned short*)(ws + 40 * MB);  // 4MB
  unsigned short* posb = (unsigned short*)(ws + 44 * MB);  // 4MB
  unsigned short* wkb  = (unsigned short*)(ws + 48 * MB);  // 2MB (contig with wvb!)
  unsigned short* wvb  = (unsigned short*)(ws + 50 * MB);  // 2MB
  unsigned short* wqb  = (unsigned short*)(ws + 52 * MB);
  unsigned short* wpb  = (unsigned short*)(ws + 54 * MB);
  unsigned short* wob  = (unsigned short*)(ws + 56 * MB);
  unsigned short* mkb  = (unsigned short*)(ws + 58 * MB);  // row-major mask 8MB

  convert_all<<<2048, 256, 0, stream>>>(key, query, memory, pos, mask,
      Wk, Wv, Wq, Wp, Wo, kcat, qry, posb, wkb, wvb, wqb, wpb, wob, mkb);

  // ALL projections in one 768-block launch (kv 512 + q 128 + pos 128)
  gemm_proj<<<768, 256, 0, stream>>>(kcat, qry, posb, wkb, wqb, wpb,
      bk, bv, bq, bp, u, v, kpk, vpk, qupk, qvpk, ppk);

  attn_fused<<<2048, 1024, 0, stream>>>(qupk, qvpk, kpk, ppk, vpk, mkb,
      outAW, cvb);

  gemm_out<<<dim3(8, 32), 256, 0, stream>>>(cvb, wob, bo, outCV);
}